// Round 1
// baseline (3497.480 us; speedup 1.0000x reference)
//
#include <hip/hip_runtime.h>
#include <hip/hip_bf16.h>
#include <math.h>

// Problem constants
#define Bn      32768
#define IN_DIM  256
#define N_HDIM  512
#define QDIM    1024
#define N_EMBD  256

// Output layout (float32): recon [B*256] | khot [B*1024] | scalar [1] | k [B]
#define OUT_RECON_OFF  0
#define OUT_KHOT_OFF   ((size_t)Bn * IN_DIM)                 // 8388608
#define OUT_SCALAR_OFF (OUT_KHOT_OFF + (size_t)Bn * QDIM)    // 41943040
#define OUT_K_OFF      (OUT_SCALAR_OFF + 1)                  // 41943041

// ---------------------------------------------------------------------------
// Generic tiled fp32 GEMM: C[M,N] = act( A[M,K] * W[N,K]^T + bias ) (/ k[row])
// BM=BN=64, BK=32, 256 threads, 4x4 outputs/thread.
// CONCAT: A is [x | logits] with x stride 256 (K<256) and A2 stride 1024.
// ---------------------------------------------------------------------------
#define BM 64
#define BN 64
#define BK 32

template<bool RELU, bool BIAS, bool INVK, bool CONCAT>
__global__ __launch_bounds__(256) void gemm_nt(
    const float* __restrict__ A, const float* __restrict__ A2,
    const float* __restrict__ W, const float* __restrict__ bias,
    const float* __restrict__ kvals, float* __restrict__ C,
    int M, int N, int K)
{
    __shared__ float As[BK][BM + 1];
    __shared__ float Ws[BK][BN + 1];
    const int tid = threadIdx.x;
    const int m0 = blockIdx.y * BM;
    const int n0 = blockIdx.x * BN;
    const int ty = tid >> 4, tx = tid & 15;

    float acc[4][4] = {};

    for (int k0 = 0; k0 < K; k0 += BK) {
        // ---- stage A tile (64 rows x 32 k) ----
        const float* Ap;
        int lda, kk0;
        if (CONCAT && k0 >= IN_DIM) { Ap = A2; lda = QDIM; kk0 = k0 - IN_DIM; }
        else                        { Ap = A;  lda = CONCAT ? IN_DIM : K; kk0 = k0; }
#pragma unroll
        for (int t = 0; t < 2; t++) {
            int f = tid + t * 256;            // 512 float4s total
            int row = f >> 3;
            int kc4 = (f & 7) * 4;
            float4 v = *(const float4*)(Ap + (size_t)(m0 + row) * lda + kk0 + kc4);
            As[kc4 + 0][row] = v.x; As[kc4 + 1][row] = v.y;
            As[kc4 + 2][row] = v.z; As[kc4 + 3][row] = v.w;
        }
        // ---- stage W tile (64 n-rows x 32 k) ----
#pragma unroll
        for (int t = 0; t < 2; t++) {
            int f = tid + t * 256;
            int row = f >> 3;
            int kc4 = (f & 7) * 4;
            float4 v = *(const float4*)(W + (size_t)(n0 + row) * K + k0 + kc4);
            Ws[kc4 + 0][row] = v.x; Ws[kc4 + 1][row] = v.y;
            Ws[kc4 + 2][row] = v.z; Ws[kc4 + 3][row] = v.w;
        }
        __syncthreads();

#pragma unroll
        for (int kk = 0; kk < BK; kk++) {
            float a[4], b[4];
#pragma unroll
            for (int i = 0; i < 4; i++) a[i] = As[kk][ty * 4 + i];
#pragma unroll
            for (int j = 0; j < 4; j++) b[j] = Ws[kk][tx * 4 + j];
#pragma unroll
            for (int i = 0; i < 4; i++)
#pragma unroll
                for (int j = 0; j < 4; j++)
                    acc[i][j] = fmaf(a[i], b[j], acc[i][j]);
        }
        __syncthreads();
    }

    // ---- epilogue ----
    float bv[4] = {0.f, 0.f, 0.f, 0.f};
    if (BIAS) {
#pragma unroll
        for (int j = 0; j < 4; j++) bv[j] = bias[n0 + tx * 4 + j];
    }
#pragma unroll
    for (int i = 0; i < 4; i++) {
        int r = m0 + ty * 4 + i;
        float inv = 1.0f;
        if (INVK) inv = 1.0f / kvals[r];
        float4 o;
        o.x = acc[i][0] + bv[0];
        o.y = acc[i][1] + bv[1];
        o.z = acc[i][2] + bv[2];
        o.w = acc[i][3] + bv[3];
        if (INVK) { o.x *= inv; o.y *= inv; o.z *= inv; o.w *= inv; }
        if (RELU) {
            o.x = fmaxf(o.x, 0.f); o.y = fmaxf(o.y, 0.f);
            o.z = fmaxf(o.z, 0.f); o.w = fmaxf(o.w, 0.f);
        }
        *(float4*)(C + (size_t)r * N + n0 + tx * 4) = o;
    }
}

// ---------------------------------------------------------------------------
// K3 GEMV: z = h[B,512] . w3 + b3 ; k = clip(sigmoid(z)*1024 * sigmoid(ks)*2, 1, 1024)
// one wave per row, 4 rows per block
// ---------------------------------------------------------------------------
__global__ __launch_bounds__(256) void kpred_final(
    const float* __restrict__ h, const float* __restrict__ w3,
    const float* __restrict__ b3, const float* __restrict__ kscale,
    float* __restrict__ kout, float* __restrict__ scalar_out)
{
    int wid = threadIdx.x >> 6, lane = threadIdx.x & 63;
    int row = blockIdx.x * 4 + wid;
    const float* hr = h + (size_t)row * N_HDIM;
    float s = 0.f;
#pragma unroll
    for (int t = 0; t < N_HDIM / 64; t++) {
        int j = lane + t * 64;
        s = fmaf(hr[j], w3[j], s);
    }
#pragma unroll
    for (int off = 32; off > 0; off >>= 1) s += __shfl_down(s, off);
    if (lane == 0) {
        float z = s + b3[0];
        float kk = (1.0f / (1.0f + expf(-z))) * 1024.0f;
        float sc = 1.0f / (1.0f + expf(-kscale[0]));
        float kv = fminf(fmaxf(kk * sc * 2.0f, 1.0f), 1024.0f);
        kout[row] = kv;
    }
    if (blockIdx.x == 0 && threadIdx.x == 0) scalar_out[0] = 0.0f;
}

// ---------------------------------------------------------------------------
// khot: per-row exact top-m mask (m = ceil(k)), ties broken by lowest index.
// In-place: reads logits from `data` row, overwrites with 0/1 mask.
// Radix select on sortable-uint keys, 4 passes of 8 bits, LDS histogram.
// One block (256 threads) per row.
// ---------------------------------------------------------------------------
__global__ __launch_bounds__(256) void khot_kernel(
    float* __restrict__ data, const float* __restrict__ kvals)
{
    __shared__ unsigned u_s[QDIM];
    __shared__ unsigned hist[256];
    __shared__ unsigned s_chosen, s_remaining;

    const int row = blockIdx.x;
    const int tid = threadIdx.x;
    float* rowp = data + (size_t)row * QDIM;

#pragma unroll
    for (int t = 0; t < 4; t++) {
        int i = tid + t * 256;
        unsigned s = __float_as_uint(rowp[i]);
        // monotone map: larger float -> larger uint
        u_s[i] = (s & 0x80000000u) ? ~s : (s | 0x80000000u);
    }
    float kc = kvals[row];
    int m = (int)ceilf(kc);
    if (m < 1) m = 1;
    if (m > QDIM) m = QDIM;
    __syncthreads();

    unsigned prefix = 0;
    unsigned remaining = (unsigned)m;
    for (int shift = 24; shift >= 0; shift -= 8) {
        hist[tid] = 0;
        __syncthreads();
#pragma unroll
        for (int t = 0; t < 4; t++) {
            unsigned u = u_s[tid + t * 256];
            bool ok = (shift == 24) || ((u >> (shift + 8)) == prefix);
            if (ok) atomicAdd(&hist[(u >> shift) & 255u], 1u);
        }
        __syncthreads();
        if (tid == 0) {
            unsigned cum = 0;
            for (int b = 255; b >= 0; b--) {
                unsigned c = hist[b];
                if (cum + c >= remaining || b == 0) {
                    s_chosen = (unsigned)b;
                    s_remaining = remaining - cum;
                    break;
                }
                cum += c;
            }
        }
        __syncthreads();
        prefix = (prefix << 8) | s_chosen;
        remaining = s_remaining;
        __syncthreads();   // hist reused next pass; s_* re-written by tid 0
    }

    const unsigned um = prefix;       // exact bit pattern of m-th largest
    const unsigned need = remaining;  // how many ties (==um) to take, by index order

#pragma unroll
    for (int t = 0; t < 4; t++) {
        int i = tid + t * 256;
        unsigned u = u_s[i];
        bool sel;
        if (u > um) sel = true;
        else if (u < um) sel = false;
        else {
            unsigned r = 0;
            for (int j = 0; j < i; j++) r += (u_s[j] == um) ? 1u : 0u;
            sel = (r < need);
        }
        rowp[i] = sel ? 1.0f : 0.0f;
    }
}

// ---------------------------------------------------------------------------
extern "C" void kernel_launch(void* const* d_in, const int* in_sizes, int n_in,
                              void* d_out, int out_size, void* d_ws, size_t ws_size,
                              hipStream_t stream) {
    const float* x     = (const float*)d_in[0];
    const float* W_e1  = (const float*)d_in[1];
    const float* b_e1  = (const float*)d_in[2];
    const float* W_e2  = (const float*)d_in[3];
    const float* b_e2  = (const float*)d_in[4];
    const float* W_cb  = (const float*)d_in[5];
    const float* W_d1  = (const float*)d_in[6];
    const float* b_d1  = (const float*)d_in[7];
    const float* W_d2  = (const float*)d_in[8];
    const float* b_d2  = (const float*)d_in[9];
    const float* W_k1  = (const float*)d_in[10];
    const float* b_k1  = (const float*)d_in[11];
    const float* W_k2  = (const float*)d_in[12];
    const float* b_k2  = (const float*)d_in[13];
    const float* W_k3  = (const float*)d_in[14];
    const float* b_k3  = (const float*)d_in[15];
    const float* k_scl = (const float*)d_in[16];

    float* out   = (float*)d_out;
    float* recon = out + OUT_RECON_OFF;
    float* khot  = out + OUT_KHOT_OFF;    // staged: logits live here until khot_kernel
    float* scl   = out + OUT_SCALAR_OFF;
    float* kout  = out + OUT_K_OFF;

    // workspace: two B x 512 fp32 ping-pong buffers (134 MB total)
    float* buf1 = (float*)d_ws;                       // B*512
    float* buf2 = buf1 + (size_t)Bn * N_HDIM;         // B*512

    const dim3 blk(256);

    // E1: h1 = relu(x @ W_e1^T + b_e1)           [B,512]  -> buf1
    gemm_nt<true, true, false, false><<<dim3(N_HDIM / BN, Bn / BM), blk, 0, stream>>>(
        x, nullptr, W_e1, b_e1, nullptr, buf1, Bn, N_HDIM, IN_DIM);

    // E2: logits = h1 @ W_e2^T + b_e2            [B,1024] -> khot region of d_out
    gemm_nt<false, true, false, false><<<dim3(QDIM / BN, Bn / BM), blk, 0, stream>>>(
        buf1, nullptr, W_e2, b_e2, nullptr, khot, Bn, QDIM, N_HDIM);

    // K1: hk1 = relu([x|logits] @ W_k1^T + b_k1) [B,512]  -> buf1 (h1 dead)
    gemm_nt<true, true, false, true><<<dim3(N_HDIM / BN, Bn / BM), blk, 0, stream>>>(
        x, khot, W_k1, b_k1, nullptr, buf1, Bn, N_HDIM, IN_DIM + QDIM);

    // K2: hk2 = relu(hk1 @ W_k2^T + b_k2)        [B,512]  -> buf2
    gemm_nt<true, true, false, false><<<dim3(N_HDIM / BN, Bn / BM), blk, 0, stream>>>(
        buf1, nullptr, W_k2, b_k2, nullptr, buf2, Bn, N_HDIM, N_HDIM);

    // K3: k = clip(sigmoid(hk2 . w3 + b3)*1024 * sigmoid(ks)*2, 1, 1024) -> kout
    kpred_final<<<dim3(Bn / 4), blk, 0, stream>>>(buf2, W_k3, b_k3, k_scl, kout, scl);

    // khot: in-place logits -> 0/1 mask (exact top-ceil(k), stable ties)
    khot_kernel<<<dim3(Bn), blk, 0, stream>>>(khot, kout);

    // CB: q = (khot @ W_cb^T) / k                [B,256]  -> buf1
    gemm_nt<false, false, true, false><<<dim3(N_EMBD / BN, Bn / BM), blk, 0, stream>>>(
        khot, nullptr, W_cb, nullptr, kout, buf1, Bn, N_EMBD, QDIM);

    // D1: hd1 = relu(q @ W_d1^T + b_d1)          [B,512]  -> buf2
    gemm_nt<true, true, false, false><<<dim3(N_HDIM / BN, Bn / BM), blk, 0, stream>>>(
        buf1, nullptr, W_d1, b_d1, nullptr, buf2, Bn, N_HDIM, N_EMBD);

    // D2: recon = hd1 @ W_d2^T + b_d2            [B,256]  -> d_out
    gemm_nt<false, true, false, false><<<dim3(IN_DIM / BN, Bn / BM), blk, 0, stream>>>(
        buf2, nullptr, W_d2, b_d2, nullptr, recon, Bn, IN_DIM, N_HDIM);
}

// Round 2
// 722.480 us; speedup vs baseline: 4.8409x; 4.8409x over previous
//
#include <hip/hip_runtime.h>
#include <hip/hip_bf16.h>
#include <math.h>

typedef __hip_bfloat16 bf16;
using frag8 = __attribute__((ext_vector_type(8))) short;   // 8 bf16 = 4 VGPRs
using f32x4 = __attribute__((ext_vector_type(4))) float;   // MFMA accumulator

// Problem constants
#define Bn      32768
#define IN_DIM  256
#define N_HDIM  512
#define QDIM    1024
#define N_EMBD  256

// Output layout (float32): recon [B*256] | khot [B*1024] | scalar [1] | k [B]
#define OUT_KHOT_OFF   ((size_t)Bn * IN_DIM)
#define OUT_SCALAR_OFF (OUT_KHOT_OFF + (size_t)Bn * QDIM)
#define OUT_K_OFF      (OUT_SCALAR_OFF + 1)

// Workspace layout (bytes). Weights-as-bf16 (4 MiB), then two bf16 activation
// ping-pong buffers (32 MiB each).
#define WS_WE1   0
#define WS_WE2   (WS_WE1 + 512*256*2)
#define WS_WCB   (WS_WE2 + 1024*512*2)
#define WS_WD1   (WS_WCB + 256*1024*2)
#define WS_WD2   (WS_WD1 + 512*256*2)
#define WS_WK1   (WS_WD2 + 256*512*2)
#define WS_WK2   (WS_WK1 + 512*1280*2)
#define WS_BUFA  (WS_WK2 + 512*512*2)            // 4 MiB mark
#define WS_BUFB  (WS_BUFA + (size_t)Bn*512*2)

__device__ inline void async_copy16(const void* g, void* l) {
    __builtin_amdgcn_global_load_lds(
        (const __attribute__((address_space(1))) void*)g,
        (__attribute__((address_space(3))) void*)l, 16, 0, 0);
}

// ---------------------------------------------------------------------------
// fp32 -> bf16 conversion (weights), 4 elems/thread
// ---------------------------------------------------------------------------
__global__ void f2b_kernel(const float* __restrict__ s, bf16* __restrict__ d, int n) {
    int i = (blockIdx.x * 256 + threadIdx.x) * 4;
    if (i < n) {
        float4 v = *(const float4*)(s + i);
        union { short4 s4; bf16 h[4]; } u;
        u.h[0] = __float2bfloat16(v.x); u.h[1] = __float2bfloat16(v.y);
        u.h[2] = __float2bfloat16(v.z); u.h[3] = __float2bfloat16(v.w);
        *(short4*)(d + i) = u.s4;
    }
}

// ---------------------------------------------------------------------------
// bf16 MFMA GEMM: C[M,N] = act( A[M,K] @ W[N,K]^T + bias ) (* 1/k[row])
// 128x128 tile, BK=64, 256 threads (4 waves, 2x2), 16x16x32 MFMA, 4x4 tiles/wave.
// LDS: XOR-swizzled chunk layout (chunk g of row r stored at g^(r&7)) so
// ds_read_b128 fragment reads are bank-conflict-free while staying compatible
// with global_load_lds's "wave-uniform base + lane*16" destination rule.
// ASRC: 0 = A is bf16 (global_load_lds); 1 = A is fp32 (convert-stage);
//       2 = A is concat [fp32 Ap stride lda | fp32 A2p stride lda2] split at col 256.
// ---------------------------------------------------------------------------
template<int ASRC, int OUTF, int RELU, int BIAS, int INVK>
__global__ __launch_bounds__(256) void mgemm(
    const void* __restrict__ Ap, const void* __restrict__ A2p,
    const bf16* __restrict__ W, const float* __restrict__ bias,
    const float* __restrict__ kv, void* __restrict__ Cp,
    int N, int K, int lda, int lda2)
{
    __shared__ __align__(16) bf16 sA[128 * 64];
    __shared__ __align__(16) bf16 sB[128 * 64];

    const int tid = threadIdx.x;
    const int wv = tid >> 6, ln = tid & 63;
    const int wr = wv >> 1, wc = wv & 1;
    const int m0 = blockIdx.y * 128;
    const int n0 = blockIdx.x * 128;
    const int lm = ln & 15, q = ln >> 4;

    f32x4 acc[4][4];
#pragma unroll
    for (int i = 0; i < 4; i++)
#pragma unroll
        for (int j = 0; j < 4; j++)
            acc[i][j] = (f32x4){0.f, 0.f, 0.f, 0.f};

    for (int k0 = 0; k0 < K; k0 += 64) {
        // ---- stage A (128 rows x 64 k bf16 = 1024 x 16B chunks) ----
        if (ASRC == 0) {
            const bf16* A = (const bf16*)Ap;
#pragma unroll
            for (int i = 0; i < 4; i++) {
                int c = wv * 256 + i * 64 + ln;       // wave-uniform base + lane
                int row = c >> 3;
                int g = (c & 7) ^ (row & 7);          // fetch the chunk that lands here
                async_copy16(A + (size_t)(m0 + row) * lda + k0 + g * 8, &sA[c * 8]);
            }
        } else {
            const float* Af; int col0, ldf;
            if (ASRC == 2 && k0 >= IN_DIM) { Af = (const float*)A2p; col0 = k0 - IN_DIM; ldf = lda2; }
            else                           { Af = (const float*)Ap;  col0 = k0;          ldf = lda; }
#pragma unroll
            for (int i = 0; i < 4; i++) {
                int c = wv * 256 + i * 64 + ln;
                int row = c >> 3;
                int g = (c & 7) ^ (row & 7);
                const float* src = Af + (size_t)(m0 + row) * ldf + col0 + g * 8;
                float4 v0 = *(const float4*)src;
                float4 v1 = *(const float4*)(src + 4);
                union { frag8 s; bf16 h[8]; } u;
                u.h[0] = __float2bfloat16(v0.x); u.h[1] = __float2bfloat16(v0.y);
                u.h[2] = __float2bfloat16(v0.z); u.h[3] = __float2bfloat16(v0.w);
                u.h[4] = __float2bfloat16(v1.x); u.h[5] = __float2bfloat16(v1.y);
                u.h[6] = __float2bfloat16(v1.z); u.h[7] = __float2bfloat16(v1.w);
                *(frag8*)(&sA[c * 8]) = u.s;
            }
        }
        // ---- stage W tile ----
#pragma unroll
        for (int i = 0; i < 4; i++) {
            int c = wv * 256 + i * 64 + ln;
            int row = c >> 3;
            int g = (c & 7) ^ (row & 7);
            async_copy16(W + (size_t)(n0 + row) * K + k0 + g * 8, &sB[c * 8]);
        }
        __syncthreads();

        // ---- 32 MFMAs over BK=64 ----
#pragma unroll
        for (int kk = 0; kk < 2; kk++) {
            frag8 af[4], bfr[4];
#pragma unroll
            for (int t = 0; t < 4; t++) {
                int r = wr * 64 + t * 16 + lm;
                af[t] = *(const frag8*)&sA[r * 64 + (((kk * 4 + q) ^ (r & 7)) * 8)];
                int n = wc * 64 + t * 16 + lm;
                bfr[t] = *(const frag8*)&sB[n * 64 + (((kk * 4 + q) ^ (n & 7)) * 8)];
            }
#pragma unroll
            for (int mt = 0; mt < 4; mt++)
#pragma unroll
                for (int nt = 0; nt < 4; nt++)
                    acc[mt][nt] = __builtin_amdgcn_mfma_f32_16x16x32_bf16(
                        af[mt], bfr[nt], acc[mt][nt], 0, 0, 0);
        }
        __syncthreads();
    }

    // ---- epilogue: C layout col=lane&15, row=(lane>>4)*4+reg ----
#pragma unroll
    for (int mt = 0; mt < 4; mt++) {
#pragma unroll
        for (int r = 0; r < 4; r++) {
            int row = m0 + wr * 64 + mt * 16 + q * 4 + r;
            float scale = 1.0f;
            if (INVK) scale = 1.0f / kv[row];
#pragma unroll
            for (int nt = 0; nt < 4; nt++) {
                int col = n0 + wc * 64 + nt * 16 + lm;
                float v = acc[mt][nt][r];
                if (BIAS) v += bias[col];
                if (INVK) v *= scale;
                if (RELU) v = fmaxf(v, 0.f);
                if (OUTF) ((float*)Cp)[(size_t)row * N + col] = v;
                else      ((bf16*)Cp)[(size_t)row * N + col] = __float2bfloat16(v);
            }
        }
    }
}

// ---------------------------------------------------------------------------
// K3 GEMV on bf16 h: k = clip(sigmoid(h.w3+b3)*1024 * sigmoid(ks)*2, 1, 1024)
// ---------------------------------------------------------------------------
__global__ __launch_bounds__(256) void kpred_final(
    const bf16* __restrict__ h, const float* __restrict__ w3,
    const float* __restrict__ b3, const float* __restrict__ kscale,
    float* __restrict__ kout, float* __restrict__ scalar_out)
{
    int wid = threadIdx.x >> 6, lane = threadIdx.x & 63;
    int row = blockIdx.x * 4 + wid;
    const bf16* hr = h + (size_t)row * N_HDIM;
    float s = 0.f;
#pragma unroll
    for (int t = 0; t < N_HDIM / 64; t++) {
        int j = lane + t * 64;
        s = fmaf(__bfloat162float(hr[j]), w3[j], s);
    }
#pragma unroll
    for (int off = 32; off > 0; off >>= 1) s += __shfl_down(s, off);
    if (lane == 0) {
        float z = s + b3[0];
        float kk = (1.0f / (1.0f + expf(-z))) * 1024.0f;
        float sc = 1.0f / (1.0f + expf(-kscale[0]));
        kout[row] = fminf(fmaxf(kk * sc * 2.0f, 1.0f), 1024.0f);
    }
    if (blockIdx.x == 0 && threadIdx.x == 0) scalar_out[0] = 0.0f;
}

// ---------------------------------------------------------------------------
// khot: per-row top-m mask (m=ceil(k)), ties by lowest index. In-place fp32.
// Radix select, 4x8-bit passes; bucket scan = parallel suffix sum (8 steps).
// ---------------------------------------------------------------------------
__global__ __launch_bounds__(256) void khot_kernel(
    float* __restrict__ data, const float* __restrict__ kvals)
{
    __shared__ unsigned u_s[QDIM];
    __shared__ unsigned hist[256];
    __shared__ unsigned s_chosen, s_remaining;

    const int row = blockIdx.x;
    const int tid = threadIdx.x;
    float* rowp = data + (size_t)row * QDIM;

#pragma unroll
    for (int t = 0; t < 4; t++) {
        int i = tid + t * 256;
        unsigned s = __float_as_uint(rowp[i]);
        u_s[i] = (s & 0x80000000u) ? ~s : (s | 0x80000000u);  // sortable uint
    }
    int m = (int)ceilf(kvals[row]);
    if (m < 1) m = 1;
    if (m > QDIM) m = QDIM;
    __syncthreads();

    unsigned prefix = 0;
    unsigned remaining = (unsigned)m;
    for (int shift = 24; shift >= 0; shift -= 8) {
        hist[tid] = 0;
        __syncthreads();
#pragma unroll
        for (int t = 0; t < 4; t++) {
            unsigned u = u_s[tid + t * 256];
            bool ok = (shift == 24) || ((u >> (shift + 8)) == prefix);
            if (ok) atomicAdd(&hist[(u >> shift) & 255u], 1u);
        }
        __syncthreads();
        // suffix sum: hist[b] <- sum_{b'>=b} hist[b']
        for (int off = 1; off < 256; off <<= 1) {
            unsigned v = (tid + off < 256) ? hist[tid + off] : 0u;
            __syncthreads();
            hist[tid] += v;
            __syncthreads();
        }
        unsigned sb = hist[tid];
        unsigned sb1 = (tid < 255) ? hist[tid + 1] : 0u;
        if (sb >= remaining && sb1 < remaining) {
            s_chosen = (unsigned)tid;
            s_remaining = remaining - sb1;
        }
        __syncthreads();
        prefix = (prefix << 8) | s_chosen;
        remaining = s_remaining;
        __syncthreads();
    }

    const unsigned um = prefix;
    const unsigned need = remaining;
#pragma unroll
    for (int t = 0; t < 4; t++) {
        int i = tid + t * 256;
        unsigned u = u_s[i];
        bool sel;
        if (u > um) sel = true;
        else if (u < um) sel = false;
        else {
            unsigned r = 0;
            for (int j = 0; j < i; j++) r += (u_s[j] == um) ? 1u : 0u;
            sel = (r < need);
        }
        rowp[i] = sel ? 1.0f : 0.0f;
    }
}

// ---------------------------------------------------------------------------
extern "C" void kernel_launch(void* const* d_in, const int* in_sizes, int n_in,
                              void* d_out, int out_size, void* d_ws, size_t ws_size,
                              hipStream_t stream) {
    const float* x     = (const float*)d_in[0];
    const float* W_e1  = (const float*)d_in[1];
    const float* b_e1  = (const float*)d_in[2];
    const float* W_e2  = (const float*)d_in[3];
    const float* b_e2  = (const float*)d_in[4];
    const float* W_cb  = (const float*)d_in[5];
    const float* W_d1  = (const float*)d_in[6];
    const float* b_d1  = (const float*)d_in[7];
    const float* W_d2  = (const float*)d_in[8];
    const float* b_d2  = (const float*)d_in[9];
    const float* W_k1  = (const float*)d_in[10];
    const float* b_k1  = (const float*)d_in[11];
    const float* W_k2  = (const float*)d_in[12];
    const float* b_k2  = (const float*)d_in[13];
    const float* W_k3  = (const float*)d_in[14];
    const float* b_k3  = (const float*)d_in[15];
    const float* k_scl = (const float*)d_in[16];

    float* out    = (float*)d_out;
    float* recon  = out;
    float* logits = out + OUT_KHOT_OFF;   // logits staged fp32 in khot slot, masked in place
    float* scl    = out + OUT_SCALAR_OFF;
    float* kout   = out + OUT_K_OFF;

    char* ws = (char*)d_ws;
    bf16* wb_e1 = (bf16*)(ws + WS_WE1);
    bf16* wb_e2 = (bf16*)(ws + WS_WE2);
    bf16* wb_cb = (bf16*)(ws + WS_WCB);
    bf16* wb_d1 = (bf16*)(ws + WS_WD1);
    bf16* wb_d2 = (bf16*)(ws + WS_WD2);
    bf16* wb_k1 = (bf16*)(ws + WS_WK1);
    bf16* wb_k2 = (bf16*)(ws + WS_WK2);
    bf16* bufA  = (bf16*)(ws + WS_BUFA);
    bf16* bufB  = (bf16*)(ws + WS_BUFB);

    // weights -> bf16
    f2b_kernel<<<dim3(512 * 256 / 1024),  256, 0, stream>>>(W_e1, wb_e1, 512 * 256);
    f2b_kernel<<<dim3(1024 * 512 / 1024), 256, 0, stream>>>(W_e2, wb_e2, 1024 * 512);
    f2b_kernel<<<dim3(256 * 1024 / 1024), 256, 0, stream>>>(W_cb, wb_cb, 256 * 1024);
    f2b_kernel<<<dim3(512 * 256 / 1024),  256, 0, stream>>>(W_d1, wb_d1, 512 * 256);
    f2b_kernel<<<dim3(256 * 512 / 1024),  256, 0, stream>>>(W_d2, wb_d2, 256 * 512);
    f2b_kernel<<<dim3(512 * 1280 / 1024), 256, 0, stream>>>(W_k1, wb_k1, 512 * 1280);
    f2b_kernel<<<dim3(512 * 512 / 1024),  256, 0, stream>>>(W_k2, wb_k2, 512 * 512);

    const dim3 blk(256);
    const dim3 gM(1, Bn / 128);  // y = M blocks

    // E1: h1 = relu(x @ We1^T + b) -> bufA (bf16)     A: fp32 x
    mgemm<1, 0, 1, 1, 0><<<dim3(512 / 128, Bn / 128), blk, 0, stream>>>(
        x, nullptr, wb_e1, b_e1, nullptr, bufA, 512, 256, 256, 0);
    // E2: logits = h1 @ We2^T + b -> d_out khot slot (fp32)
    mgemm<0, 1, 0, 1, 0><<<dim3(1024 / 128, Bn / 128), blk, 0, stream>>>(
        bufA, nullptr, wb_e2, b_e2, nullptr, logits, 1024, 512, 512, 0);
    // K1: hk1 = relu([x|logits] @ Wk1^T + b) -> bufA   A: fp32 concat
    mgemm<2, 0, 1, 1, 0><<<dim3(512 / 128, Bn / 128), blk, 0, stream>>>(
        x, logits, wb_k1, b_k1, nullptr, bufA, 512, 1280, 256, 1024);
    // K2: hk2 = relu(hk1 @ Wk2^T + b) -> bufB
    mgemm<0, 0, 1, 1, 0><<<dim3(512 / 128, Bn / 128), blk, 0, stream>>>(
        bufA, nullptr, wb_k2, b_k2, nullptr, bufB, 512, 512, 512, 0);
    // K3 GEMV -> kout, scalar
    kpred_final<<<dim3(Bn / 4), blk, 0, stream>>>(bufB, W_k3, b_k3, k_scl, kout, scl);
    // khot in place on logits (fp32)
    khot_kernel<<<dim3(Bn), blk, 0, stream>>>(logits, kout);
    // CB: q = (khot/k) @ Wcb^T -> bufA (bf16)          A: fp32 khot
    mgemm<1, 0, 0, 0, 1><<<dim3(256 / 128, Bn / 128), blk, 0, stream>>>(
        logits, nullptr, wb_cb, nullptr, kout, bufA, 256, 1024, 1024, 0);
    // D1: hd1 = relu(q @ Wd1^T + b) -> bufB
    mgemm<0, 0, 1, 1, 0><<<dim3(512 / 128, Bn / 128), blk, 0, stream>>>(
        bufA, nullptr, wb_d1, b_d1, nullptr, bufB, 512, 256, 256, 0);
    // D2: recon = hd1 @ Wd2^T + b -> d_out (fp32)
    mgemm<0, 1, 0, 1, 0><<<dim3(256 / 128, Bn / 128), blk, 0, stream>>>(
        bufB, nullptr, wb_d2, b_d2, nullptr, recon, 256, 512, 512, 0);
}

// Round 3
// 547.992 us; speedup vs baseline: 6.3824x; 1.3184x over previous
//
#include <hip/hip_runtime.h>
#include <hip/hip_bf16.h>
#include <math.h>

typedef __hip_bfloat16 bf16;
typedef unsigned short u16;
using frag8 = __attribute__((ext_vector_type(8))) short;   // 8 bf16 = 4 VGPRs
using f32x4 = __attribute__((ext_vector_type(4))) float;   // MFMA accumulator
using u16x8 = __attribute__((ext_vector_type(8))) unsigned short;

// Problem constants
#define Bn      32768
#define IN_DIM  256
#define N_HDIM  512
#define QDIM    1024
#define N_EMBD  256

// Output layout (float32): recon [B*256] | khot [B*1024] | scalar [1] | k [B]
#define OUT_KHOT_OFF   ((size_t)Bn * IN_DIM)
#define OUT_SCALAR_OFF (OUT_KHOT_OFF + (size_t)Bn * QDIM)
#define OUT_K_OFF      (OUT_SCALAR_OFF + 1)

// Workspace layout (bytes): bf16 weights (4 MiB) | xb | kpart | bufA | bufB
#define WS_WE1   0
#define WS_WE2   (WS_WE1 + 512*256*2)
#define WS_WCB   (WS_WE2 + 1024*512*2)
#define WS_WD1   (WS_WCB + 256*1024*2)
#define WS_WD2   (WS_WD1 + 512*256*2)
#define WS_WK1   (WS_WD2 + 256*512*2)
#define WS_WK2   (WS_WK1 + 512*1280*2)
#define WS_XB    (WS_WK2 + 512*512*2)                     // 4 MiB mark
#define WS_KPART (WS_XB + (size_t)Bn*256*2)               // +16.7 MB
#define WS_BUFA  (WS_KPART + (size_t)Bn*4)                // +128 KB
#define WS_BUFB  (WS_BUFA + (size_t)Bn*512*2)             // +33.5 MB
// total: ~121.7 MB (fits the 134 MB proven in round 0)

__device__ inline void async_copy16(const void* g, void* l) {
    __builtin_amdgcn_global_load_lds(
        (const __attribute__((address_space(1))) void*)g,
        (__attribute__((address_space(3))) void*)l, 16, 0, 0);
}

// ---------------------------------------------------------------------------
// fp32 -> bf16 conversion, 4 elems/thread
// ---------------------------------------------------------------------------
__global__ void f2b_kernel(const float* __restrict__ s, bf16* __restrict__ d, int n) {
    int i = (blockIdx.x * 256 + threadIdx.x) * 4;
    if (i < n) {
        float4 v = *(const float4*)(s + i);
        union { short4 s4; bf16 h[4]; } u;
        u.h[0] = __float2bfloat16(v.x); u.h[1] = __float2bfloat16(v.y);
        u.h[2] = __float2bfloat16(v.z); u.h[3] = __float2bfloat16(v.w);
        *(short4*)(d + i) = u.s4;
    }
}

// ---------------------------------------------------------------------------
// bf16 MFMA GEMM: 128x128 tile, BK=64, 4 waves (2x2), 16x16x32 MFMA.
// XOR-swizzled LDS (chunk g of row r at g^(r&7)): conflict-free ds_read_b128
// while compatible with global_load_lds wave-uniform destination rule.
// ASRC: 0 = A bf16; 1 = A fp32 (convert-stage); 3 = concat bf16 [Ap | A2p]
//       split at col IN_DIM.
// OMODE: 0 = store bf16 C; 1 = store fp32 C; 2 = kdot: no C store, instead
//        atomicAdd per-row partial dot relu(C row + bias) . kv into Cp.
// ---------------------------------------------------------------------------
template<int ASRC, int OMODE, int RELU, int BIAS, int INVK>
__global__ __launch_bounds__(256) void mgemm(
    const void* __restrict__ Ap, const void* __restrict__ A2p,
    const bf16* __restrict__ W, const float* __restrict__ bias,
    const float* __restrict__ kv, void* __restrict__ Cp,
    int N, int K, int lda, int lda2)
{
    __shared__ __align__(16) bf16 sA[128 * 64];
    __shared__ __align__(16) bf16 sB[128 * 64];

    const int tid = threadIdx.x;
    const int wv = tid >> 6, ln = tid & 63;
    const int wr = wv >> 1, wc = wv & 1;
    const int m0 = blockIdx.y * 128;
    const int n0 = blockIdx.x * 128;
    const int lm = ln & 15, q = ln >> 4;

    f32x4 acc[4][4];
#pragma unroll
    for (int i = 0; i < 4; i++)
#pragma unroll
        for (int j = 0; j < 4; j++)
            acc[i][j] = (f32x4){0.f, 0.f, 0.f, 0.f};

    for (int k0 = 0; k0 < K; k0 += 64) {
        // ---- stage A (128 rows x 64 k bf16) ----
        if (ASRC == 0 || ASRC == 3) {
            const bf16* A; int ld, col0;
            if (ASRC == 3 && k0 >= IN_DIM) { A = (const bf16*)A2p; ld = lda2; col0 = k0 - IN_DIM; }
            else                           { A = (const bf16*)Ap;  ld = lda;  col0 = k0; }
#pragma unroll
            for (int i = 0; i < 4; i++) {
                int c = wv * 256 + i * 64 + ln;
                int row = c >> 3;
                int g = (c & 7) ^ (row & 7);
                async_copy16(A + (size_t)(m0 + row) * ld + col0 + g * 8, &sA[c * 8]);
            }
        } else {  // ASRC == 1: fp32 convert-stage
            const float* Af = (const float*)Ap;
#pragma unroll
            for (int i = 0; i < 4; i++) {
                int c = wv * 256 + i * 64 + ln;
                int row = c >> 3;
                int g = (c & 7) ^ (row & 7);
                const float* src = Af + (size_t)(m0 + row) * lda + k0 + g * 8;
                float4 v0 = *(const float4*)src;
                float4 v1 = *(const float4*)(src + 4);
                union { frag8 s; bf16 h[8]; } u;
                u.h[0] = __float2bfloat16(v0.x); u.h[1] = __float2bfloat16(v0.y);
                u.h[2] = __float2bfloat16(v0.z); u.h[3] = __float2bfloat16(v0.w);
                u.h[4] = __float2bfloat16(v1.x); u.h[5] = __float2bfloat16(v1.y);
                u.h[6] = __float2bfloat16(v1.z); u.h[7] = __float2bfloat16(v1.w);
                *(frag8*)(&sA[c * 8]) = u.s;
            }
        }
        // ---- stage W tile ----
#pragma unroll
        for (int i = 0; i < 4; i++) {
            int c = wv * 256 + i * 64 + ln;
            int row = c >> 3;
            int g = (c & 7) ^ (row & 7);
            async_copy16(W + (size_t)(n0 + row) * K + k0 + g * 8, &sB[c * 8]);
        }
        __syncthreads();

#pragma unroll
        for (int kk = 0; kk < 2; kk++) {
            frag8 af[4], bfr[4];
#pragma unroll
            for (int t = 0; t < 4; t++) {
                int r = wr * 64 + t * 16 + lm;
                af[t] = *(const frag8*)&sA[r * 64 + (((kk * 4 + q) ^ (r & 7)) * 8)];
                int n = wc * 64 + t * 16 + lm;
                bfr[t] = *(const frag8*)&sB[n * 64 + (((kk * 4 + q) ^ (n & 7)) * 8)];
            }
#pragma unroll
            for (int mt = 0; mt < 4; mt++)
#pragma unroll
                for (int nt = 0; nt < 4; nt++)
                    acc[mt][nt] = __builtin_amdgcn_mfma_f32_16x16x32_bf16(
                        af[mt], bfr[nt], acc[mt][nt], 0, 0, 0);
        }
        __syncthreads();
    }

    // ---- epilogue (C layout: col=lane&15, row=(lane>>4)*4+reg) ----
    if (OMODE == 2) {
        // per-row partial dot of relu(c + bias) with kv, atomicAdd into Cp[row]
        float* kpart = (float*)Cp;
#pragma unroll
        for (int mt = 0; mt < 4; mt++) {
#pragma unroll
            for (int r = 0; r < 4; r++) {
                int row = m0 + wr * 64 + mt * 16 + q * 4 + r;
                float s = 0.f;
#pragma unroll
                for (int nt = 0; nt < 4; nt++) {
                    int col = n0 + wc * 64 + nt * 16 + lm;
                    float v = acc[mt][nt][r] + bias[col];
                    v = fmaxf(v, 0.f);
                    s = fmaf(v, kv[col], s);
                }
#pragma unroll
                for (int off = 8; off > 0; off >>= 1) s += __shfl_down(s, off);
                if (lm == 0) atomicAdd(&kpart[row], s);
            }
        }
    } else {
#pragma unroll
        for (int mt = 0; mt < 4; mt++) {
#pragma unroll
            for (int r = 0; r < 4; r++) {
                int row = m0 + wr * 64 + mt * 16 + q * 4 + r;
                float scale = 1.0f;
                if (INVK) scale = 1.0f / kv[row];
#pragma unroll
                for (int nt = 0; nt < 4; nt++) {
                    int col = n0 + wc * 64 + nt * 16 + lm;
                    float v = acc[mt][nt][r];
                    if (BIAS) v += bias[col];
                    if (INVK) v *= scale;
                    if (RELU) v = fmaxf(v, 0.f);
                    if (OMODE == 1) ((float*)Cp)[(size_t)row * N + col] = v;
                    else            ((bf16*)Cp)[(size_t)row * N + col] = __float2bfloat16(v);
                }
            }
        }
    }
}

// ---------------------------------------------------------------------------
// kfinal: k = clip(sigmoid(kpart+b3)*1024 * sigmoid(ks)*2, 1, 1024)
// ---------------------------------------------------------------------------
__global__ __launch_bounds__(256) void kfinal(
    const float* __restrict__ kpart, const float* __restrict__ b3,
    const float* __restrict__ kscale, float* __restrict__ kout,
    float* __restrict__ scl)
{
    int i = blockIdx.x * 256 + threadIdx.x;
    float z = kpart[i] + b3[0];
    float kk = 1024.0f / (1.0f + expf(-z));
    float sc = 1.0f / (1.0f + expf(-kscale[0]));
    kout[i] = fminf(fmaxf(kk * sc * 2.0f, 1.0f), 1024.0f);
    if (i == 0) scl[0] = 0.0f;
}

// ---------------------------------------------------------------------------
// khot: wave-per-row top-m on 16-bit (bf16) keys, ties by lowest index.
// 2 radix passes of 8 bits, per-wave LDS histogram, zero __syncthreads.
// Reads bf16 logits from lb, writes fp32 mask to mf and bf16 mask back to lb.
// ---------------------------------------------------------------------------
__device__ inline void suffix_pick(const unsigned* h, int lane, unsigned target,
                                   unsigned& bucket, unsigned& rem)
{
    uint4 hv = *(const uint4*)(h + lane * 4);
    unsigned local = hv.x + hv.y + hv.z + hv.w;
    unsigned incl = local;
#pragma unroll
    for (int off = 1; off < 64; off <<= 1) {
        unsigned t = __shfl_down(incl, off);
        if (lane + off < 64) incl += t;
    }
    unsigned higher = incl - local;             // suffix sum of lanes > mine
    unsigned s3 = higher + hv.w;
    unsigned s2 = s3 + hv.z;
    unsigned s1 = s2 + hv.y;
    unsigned s0 = s1 + hv.x;
    unsigned suf[5] = {s0, s1, s2, s3, higher};
    int bj = -1; unsigned rm = 0;
#pragma unroll
    for (int j = 0; j < 4; j++)
        if (suf[j] >= target && suf[j + 1] < target) { bj = j; rm = target - suf[j + 1]; }
    unsigned long long mk = __ballot(bj >= 0);  // exactly one lane matches
    int src = (int)__ffsll((unsigned long long)mk) - 1;
    bucket = __shfl((unsigned)(lane * 4 + bj), src);
    rem    = __shfl(rm, src);
}

__global__ __launch_bounds__(256) void khot_kernel(
    u16* __restrict__ lb, const float* __restrict__ kvals,
    float* __restrict__ mf)
{
    __shared__ unsigned hist[4][256];
    const int w = threadIdx.x >> 6, lane = threadIdx.x & 63;
    const int row = blockIdx.x * 4 + w;
    u16* rp = lb + (size_t)row * QDIM;
    float* mfp = mf + (size_t)row * QDIM;

    u16x8 v0 = *(const u16x8*)(rp + lane * 8);
    u16x8 v1 = *(const u16x8*)(rp + 512 + lane * 8);
    unsigned key[2][8];
#pragma unroll
    for (int j = 0; j < 8; j++) {
        unsigned a = v0[j], b = v1[j];
        key[0][j] = (a & 0x8000u) ? (~a & 0xffffu) : (a | 0x8000u);
        key[1][j] = (b & 0x8000u) ? (~b & 0xffffu) : (b | 0x8000u);
    }
    int mi = (int)ceilf(kvals[row]);
    mi = mi < 1 ? 1 : (mi > QDIM ? QDIM : mi);
    const unsigned m = (unsigned)mi;
    unsigned* h = hist[w];

    // pass 1: high byte
    *(uint4*)(h + lane * 4) = make_uint4(0, 0, 0, 0);
    __threadfence_block();
#pragma unroll
    for (int c = 0; c < 2; c++)
#pragma unroll
        for (int j = 0; j < 8; j++)
            atomicAdd(&h[key[c][j] >> 8], 1u);
    __threadfence_block();
    unsigned hi, rem1;
    suffix_pick(h, lane, m, hi, rem1);

    // pass 2: low byte within chosen high bucket
    *(uint4*)(h + lane * 4) = make_uint4(0, 0, 0, 0);
    __threadfence_block();
#pragma unroll
    for (int c = 0; c < 2; c++)
#pragma unroll
        for (int j = 0; j < 8; j++)
            if ((key[c][j] >> 8) == hi) atomicAdd(&h[key[c][j] & 255u], 1u);
    __threadfence_block();
    unsigned lo, need;
    suffix_pick(h, lane, rem1, lo, need);

    const unsigned um = (hi << 8) | lo;

    // stable tie ranks by global index (chunk0 indices < chunk1 indices)
    unsigned cnt0 = 0, cnt1 = 0;
#pragma unroll
    for (int j = 0; j < 8; j++) { cnt0 += (key[0][j] == um); cnt1 += (key[1][j] == um); }
    unsigned pack = cnt0 | (cnt1 << 16);
    unsigned incl = pack;
#pragma unroll
    for (int off = 1; off < 64; off <<= 1) {
        unsigned t = __shfl_up(incl, off);
        if (lane >= off) incl += t;
    }
    unsigned excl = incl - pack;
    unsigned tot0 = __shfl(incl, 63) & 0xffffu;
    unsigned r0 = excl & 0xffffu;
    unsigned r1 = tot0 + (excl >> 16);

    float of[2][8];
    u16x8 mb0, mb1;
#pragma unroll
    for (int j = 0; j < 8; j++) {
        unsigned kv_ = key[0][j];
        bool s;
        if (kv_ > um) s = true;
        else if (kv_ == um) { s = (r0 < need); r0++; }
        else s = false;
        of[0][j] = s ? 1.0f : 0.0f;
        mb0[j] = s ? (u16)0x3F80 : (u16)0;
    }
#pragma unroll
    for (int j = 0; j < 8; j++) {
        unsigned kv_ = key[1][j];
        bool s;
        if (kv_ > um) s = true;
        else if (kv_ == um) { s = (r1 < need); r1++; }
        else s = false;
        of[1][j] = s ? 1.0f : 0.0f;
        mb1[j] = s ? (u16)0x3F80 : (u16)0;
    }
    *(float4*)(mfp + lane * 8)           = make_float4(of[0][0], of[0][1], of[0][2], of[0][3]);
    *(float4*)(mfp + lane * 8 + 4)       = make_float4(of[0][4], of[0][5], of[0][6], of[0][7]);
    *(float4*)(mfp + 512 + lane * 8)     = make_float4(of[1][0], of[1][1], of[1][2], of[1][3]);
    *(float4*)(mfp + 512 + lane * 8 + 4) = make_float4(of[1][4], of[1][5], of[1][6], of[1][7]);
    *(u16x8*)(rp + lane * 8)       = mb0;
    *(u16x8*)(rp + 512 + lane * 8) = mb1;
}

// ---------------------------------------------------------------------------
extern "C" void kernel_launch(void* const* d_in, const int* in_sizes, int n_in,
                              void* d_out, int out_size, void* d_ws, size_t ws_size,
                              hipStream_t stream) {
    const float* x     = (const float*)d_in[0];
    const float* W_e1  = (const float*)d_in[1];
    const float* b_e1  = (const float*)d_in[2];
    const float* W_e2  = (const float*)d_in[3];
    const float* b_e2  = (const float*)d_in[4];
    const float* W_cb  = (const float*)d_in[5];
    const float* W_d1  = (const float*)d_in[6];
    const float* b_d1  = (const float*)d_in[7];
    const float* W_d2  = (const float*)d_in[8];
    const float* b_d2  = (const float*)d_in[9];
    const float* W_k1  = (const float*)d_in[10];
    const float* b_k1  = (const float*)d_in[11];
    const float* W_k2  = (const float*)d_in[12];
    const float* b_k2  = (const float*)d_in[13];
    const float* W_k3  = (const float*)d_in[14];
    const float* b_k3  = (const float*)d_in[15];
    const float* k_scl = (const float*)d_in[16];

    float* out   = (float*)d_out;
    float* recon = out;
    float* maskf = out + OUT_KHOT_OFF;
    float* scl   = out + OUT_SCALAR_OFF;
    float* kout  = out + OUT_K_OFF;

    char* ws = (char*)d_ws;
    bf16* wb_e1 = (bf16*)(ws + WS_WE1);
    bf16* wb_e2 = (bf16*)(ws + WS_WE2);
    bf16* wb_cb = (bf16*)(ws + WS_WCB);
    bf16* wb_d1 = (bf16*)(ws + WS_WD1);
    bf16* wb_d2 = (bf16*)(ws + WS_WD2);
    bf16* wb_k1 = (bf16*)(ws + WS_WK1);
    bf16* wb_k2 = (bf16*)(ws + WS_WK2);
    bf16* xb    = (bf16*)(ws + WS_XB);
    float* kpart = (float*)(ws + WS_KPART);
    bf16* bufA  = (bf16*)(ws + WS_BUFA);   // 33.5 MB: h1 / hk1 / q / hd1
    bf16* bufB  = (bf16*)(ws + WS_BUFB);   // 67 MB: logits -> bf16 mask -> hd1

    hipMemsetAsync(kpart, 0, Bn * sizeof(float), stream);

    // fp32 -> bf16: weights + x
    f2b_kernel<<<dim3(512 * 256 / 1024),  256, 0, stream>>>(W_e1, wb_e1, 512 * 256);
    f2b_kernel<<<dim3(1024 * 512 / 1024), 256, 0, stream>>>(W_e2, wb_e2, 1024 * 512);
    f2b_kernel<<<dim3(256 * 1024 / 1024), 256, 0, stream>>>(W_cb, wb_cb, 256 * 1024);
    f2b_kernel<<<dim3(512 * 256 / 1024),  256, 0, stream>>>(W_d1, wb_d1, 512 * 256);
    f2b_kernel<<<dim3(256 * 512 / 1024),  256, 0, stream>>>(W_d2, wb_d2, 256 * 512);
    f2b_kernel<<<dim3(512 * 1280 / 1024), 256, 0, stream>>>(W_k1, wb_k1, 512 * 1280);
    f2b_kernel<<<dim3(512 * 512 / 1024),  256, 0, stream>>>(W_k2, wb_k2, 512 * 512);
    f2b_kernel<<<dim3(Bn * 256 / 1024),   256, 0, stream>>>(x, xb, Bn * 256);

    const dim3 blk(256);

    // E1: h1 = relu(xb @ We1^T + b) -> bufA
    mgemm<0, 0, 1, 1, 0><<<dim3(4, Bn / 128), blk, 0, stream>>>(
        xb, nullptr, wb_e1, b_e1, nullptr, bufA, 512, 256, 256, 0);
    // E2: logits(bf16) = h1 @ We2^T + b -> bufB
    mgemm<0, 0, 0, 1, 0><<<dim3(8, Bn / 128), blk, 0, stream>>>(
        bufA, nullptr, wb_e2, b_e2, nullptr, bufB, 1024, 512, 512, 0);
    // K1: hk1 = relu([xb|logits] @ Wk1^T + b) -> bufA
    mgemm<3, 0, 1, 1, 0><<<dim3(4, Bn / 128), blk, 0, stream>>>(
        xb, bufB, wb_k1, b_k1, nullptr, bufA, 512, 1280, 256, 1024);
    // K2 fused with K3 dot: kpart[row] += relu(hk1@Wk2^T + b) . w3
    mgemm<0, 2, 1, 1, 0><<<dim3(4, Bn / 128), blk, 0, stream>>>(
        bufA, nullptr, wb_k2, b_k2, W_k3, kpart, 512, 512, 512, 0);
    // k = clip(sigmoid(kpart + b3)*1024 * sigmoid(ks)*2, 1, 1024)
    kfinal<<<dim3(Bn / 256), blk, 0, stream>>>(kpart, b_k3, k_scl, kout, scl);
    // khot: bufB logits -> fp32 mask (d_out) + bf16 mask (bufB, in place)
    khot_kernel<<<dim3(Bn / 4), blk, 0, stream>>>((u16*)bufB, kout, maskf);
    // CB: q = (mask/k) @ Wcb^T -> bufA
    mgemm<0, 0, 0, 0, 1><<<dim3(2, Bn / 128), blk, 0, stream>>>(
        bufB, nullptr, wb_cb, nullptr, kout, bufA, 256, 1024, 1024, 0);
    // D1: hd1 = relu(q @ Wd1^T + b) -> bufB (logits dead)
    mgemm<0, 0, 1, 1, 0><<<dim3(4, Bn / 128), blk, 0, stream>>>(
        bufA, nullptr, wb_d1, b_d1, nullptr, bufB, 512, 256, 256, 0);
    // D2: recon = hd1 @ Wd2^T + b -> d_out (fp32)
    mgemm<0, 1, 0, 1, 0><<<dim3(2, Bn / 128), blk, 0, stream>>>(
        bufB, nullptr, wb_d2, b_d2, nullptr, recon, 256, 512, 512, 0);
}

// Round 4
// 539.378 us; speedup vs baseline: 6.4843x; 1.0160x over previous
//
#include <hip/hip_runtime.h>
#include <hip/hip_bf16.h>
#include <math.h>

typedef __hip_bfloat16 bf16;
typedef unsigned short u16;
using frag8 = __attribute__((ext_vector_type(8))) short;   // 8 bf16 = 4 VGPRs
using f32x4 = __attribute__((ext_vector_type(4))) float;   // MFMA accumulator
using u16x8 = __attribute__((ext_vector_type(8))) unsigned short;

// Problem constants
#define Bn      32768
#define IN_DIM  256
#define N_HDIM  512
#define QDIM    1024
#define N_EMBD  256

// Output layout (float32): recon [B*256] | khot [B*1024] | scalar [1] | k [B]
#define OUT_KHOT_OFF   ((size_t)Bn * IN_DIM)
#define OUT_SCALAR_OFF (OUT_KHOT_OFF + (size_t)Bn * QDIM)
#define OUT_K_OFF      (OUT_SCALAR_OFF + 1)

// Workspace layout (bytes)
#define WS_WK1   0                                   // 512x1280 bf16 (full)
#define WS_WE2   (WS_WK1 + 512*1280*2)               // 1024x512
#define WS_WCB   (WS_WE2 + 1024*512*2)               // 256x1024
#define WS_WD1   (WS_WCB + 256*1024*2)               // 512x256
#define WS_WD2   (WS_WD1 + 512*256*2)                // 256x512
#define WS_WK2   (WS_WD2 + 256*512*2)                // 512x512
#define WS_WSTK  (WS_WK2 + 512*512*2)                // 1024x256 [We1 ; Wk1[:,:256]]
#define WS_BSTK  (WS_WSTK + 1024*256*2)              // 1024 fp32 [b_e1 | 0]
#define WS_KPART (WS_BSTK + 1024*4)                  // Bn fp32
#define WS_BUFA  (WS_KPART + (size_t)Bn*4)           // Bn x 1024 bf16: [h1|kp1] -> q/...
#define WS_BUFB  (WS_BUFA + (size_t)Bn*1024*2)       // Bn x 1024 bf16: logits -> mask
#define WS_BUFC  (WS_BUFB + (size_t)Bn*1024*2)       // Bn x 512 bf16: hk1 -> hd1
// total ~172 MB

__device__ inline void async_copy16(const void* g, void* l) {
    __builtin_amdgcn_global_load_lds(
        (const __attribute__((address_space(1))) void*)g,
        (__attribute__((address_space(3))) void*)l, 16, 0, 0);
}

__device__ inline void cv4(bf16* d, float4 v) {
    union { short4 s; bf16 h[4]; } u;
    u.h[0] = __float2bfloat16(v.x); u.h[1] = __float2bfloat16(v.y);
    u.h[2] = __float2bfloat16(v.z); u.h[3] = __float2bfloat16(v.w);
    *(short4*)d = u.s;
}

// ---------------------------------------------------------------------------
// One-shot weight conversion + stacked-weight/bias build. Grid 2177 x 256,
// one float4 per thread, segment by flat id.
// ---------------------------------------------------------------------------
__global__ __launch_bounds__(256) void cvt_kernel(
    const float* __restrict__ We1, const float* __restrict__ We2,
    const float* __restrict__ Wcb, const float* __restrict__ Wd1,
    const float* __restrict__ Wd2, const float* __restrict__ Wk1,
    const float* __restrict__ Wk2, const float* __restrict__ be1,
    char* __restrict__ ws)
{
    int id = blockIdx.x * 256 + threadIdx.x;
    const float* src; bf16* dst; int off;
    if      (id < 163840) { src = Wk1; dst = (bf16*)(ws + WS_WK1); off = id; }
    else if (id < 294912) { src = We2; dst = (bf16*)(ws + WS_WE2); off = id - 163840; }
    else if (id < 360448) { src = Wcb; dst = (bf16*)(ws + WS_WCB); off = id - 294912; }
    else if (id < 393216) { src = Wd1; dst = (bf16*)(ws + WS_WD1); off = id - 360448; }
    else if (id < 425984) { src = Wd2; dst = (bf16*)(ws + WS_WD2); off = id - 393216; }
    else if (id < 491520) { src = Wk2; dst = (bf16*)(ws + WS_WK2); off = id - 425984; }
    else if (id < 524288) { src = We1; dst = (bf16*)(ws + WS_WSTK); off = id - 491520; }
    else if (id < 557056) {           // Wk1[:, :256] -> wstk rows 512..1023
        int l = id - 524288; int r = l >> 6, c4 = (l & 63) * 4;
        float4 v = *(const float4*)(Wk1 + (size_t)r * 1280 + c4);
        cv4((bf16*)(ws + WS_WSTK) + 131072 + r * 256 + c4, v);
        return;
    } else {                           // bias_stk: [b_e1 | zeros], fp32
        int l = id - 557056;           // 0..255
        float4 v = (l < 128) ? *(const float4*)(be1 + l * 4)
                             : make_float4(0.f, 0.f, 0.f, 0.f);
        *(float4*)((float*)(ws + WS_BSTK) + l * 4) = v;
        return;
    }
    float4 v = *(const float4*)(src + (size_t)off * 4);
    cv4(dst + (size_t)off * 4, v);
}

// ---------------------------------------------------------------------------
// bf16 MFMA GEMM: 128x128 tile, BK=64, 4 waves (2x2), 16x16x32 MFMA.
// XOR-swizzled LDS staging; coalesced bf16 epilogue via LDS transpose.
// ASRC: 0 = A bf16 (global_load_lds); 1 = A fp32 (convert-stage).
// OMODE: 0 = bf16 C (coalesced); 1 = fp32 C (scalar stores); 2 = kdot epilogue.
// relu_ncols (runtime): relu applied iff global col < relu_ncols.
// ACCIN: epilogue adds bf16 accin[row*ldacc + col] before relu.
// ---------------------------------------------------------------------------
template<int ASRC, int OMODE, int BIAS, int INVK, int ACCIN>
__global__ __launch_bounds__(256) void mgemm(
    const void* __restrict__ Ap, const u16* __restrict__ accin,
    const bf16* __restrict__ W, const float* __restrict__ bias,
    const float* __restrict__ kv, void* __restrict__ Cp,
    int N, int K, int lda, int ldw, int ldc, int ldacc, int relu_ncols)
{
    __shared__ __align__(16) char smem[32768];
    bf16* sA = (bf16*)smem;
    bf16* sB = (bf16*)(smem + 16384);

    const int tid = threadIdx.x;
    const int wv = tid >> 6, ln = tid & 63;
    const int wr = wv >> 1, wc = wv & 1;
    const int m0 = blockIdx.y * 128;
    const int n0 = blockIdx.x * 128;
    const int lm = ln & 15, q = ln >> 4;

    f32x4 acc[4][4];
#pragma unroll
    for (int i = 0; i < 4; i++)
#pragma unroll
        for (int j = 0; j < 4; j++)
            acc[i][j] = (f32x4){0.f, 0.f, 0.f, 0.f};

    for (int k0 = 0; k0 < K; k0 += 64) {
        // ---- stage A (128 rows x 64 k bf16) ----
        if (ASRC == 0) {
            const bf16* A = (const bf16*)Ap;
#pragma unroll
            for (int i = 0; i < 4; i++) {
                int c = wv * 256 + i * 64 + ln;
                int row = c >> 3;
                int g = (c & 7) ^ (row & 7);
                async_copy16(A + (size_t)(m0 + row) * lda + k0 + g * 8, &sA[c * 8]);
            }
        } else {  // fp32 convert-stage
            const float* Af = (const float*)Ap;
#pragma unroll
            for (int i = 0; i < 4; i++) {
                int c = wv * 256 + i * 64 + ln;
                int row = c >> 3;
                int g = (c & 7) ^ (row & 7);
                const float* src = Af + (size_t)(m0 + row) * lda + k0 + g * 8;
                float4 v0 = *(const float4*)src;
                float4 v1 = *(const float4*)(src + 4);
                union { frag8 s; bf16 h[8]; } u;
                u.h[0] = __float2bfloat16(v0.x); u.h[1] = __float2bfloat16(v0.y);
                u.h[2] = __float2bfloat16(v0.z); u.h[3] = __float2bfloat16(v0.w);
                u.h[4] = __float2bfloat16(v1.x); u.h[5] = __float2bfloat16(v1.y);
                u.h[6] = __float2bfloat16(v1.z); u.h[7] = __float2bfloat16(v1.w);
                *(frag8*)(&sA[c * 8]) = u.s;
            }
        }
        // ---- stage W tile ----
#pragma unroll
        for (int i = 0; i < 4; i++) {
            int c = wv * 256 + i * 64 + ln;
            int row = c >> 3;
            int g = (c & 7) ^ (row & 7);
            async_copy16(W + (size_t)(n0 + row) * ldw + k0 + g * 8, &sB[c * 8]);
        }
        __syncthreads();

#pragma unroll
        for (int kk = 0; kk < 2; kk++) {
            frag8 af[4], bfr[4];
#pragma unroll
            for (int t = 0; t < 4; t++) {
                int r = wr * 64 + t * 16 + lm;
                af[t] = *(const frag8*)&sA[r * 64 + (((kk * 4 + q) ^ (r & 7)) * 8)];
                int n = wc * 64 + t * 16 + lm;
                bfr[t] = *(const frag8*)&sB[n * 64 + (((kk * 4 + q) ^ (n & 7)) * 8)];
            }
#pragma unroll
            for (int mt = 0; mt < 4; mt++)
#pragma unroll
                for (int nt = 0; nt < 4; nt++)
                    acc[mt][nt] = __builtin_amdgcn_mfma_f32_16x16x32_bf16(
                        af[mt], bfr[nt], acc[mt][nt], 0, 0, 0);
        }
        __syncthreads();
    }

    // ---- epilogue (C frag layout: col=lane&15, row=(lane>>4)*4+reg) ----
    if (OMODE == 2) {
        // kdot: kpart[row] += relu(c + bias) . kv  (block partial, atomic)
        float* kpart = (float*)Cp;
#pragma unroll
        for (int mt = 0; mt < 4; mt++) {
#pragma unroll
            for (int r = 0; r < 4; r++) {
                int row = m0 + wr * 64 + mt * 16 + q * 4 + r;
                float s = 0.f;
#pragma unroll
                for (int nt = 0; nt < 4; nt++) {
                    int col = n0 + wc * 64 + nt * 16 + lm;
                    float v = acc[mt][nt][r] + bias[col];
                    v = fmaxf(v, 0.f);
                    s = fmaf(v, kv[col], s);
                }
#pragma unroll
                for (int off = 8; off > 0; off >>= 1) s += __shfl_down(s, off);
                if (lm == 0) atomicAdd(&kpart[row], s);
            }
        }
    } else if (OMODE == 1) {
        // fp32 scalar stores (recon only)
#pragma unroll
        for (int mt = 0; mt < 4; mt++) {
#pragma unroll
            for (int r = 0; r < 4; r++) {
                int row = m0 + wr * 64 + mt * 16 + q * 4 + r;
#pragma unroll
                for (int nt = 0; nt < 4; nt++) {
                    int col = n0 + wc * 64 + nt * 16 + lm;
                    float v = acc[mt][nt][r];
                    if (BIAS) v += bias[col];
                    if (col < relu_ncols) v = fmaxf(v, 0.f);
                    ((float*)Cp)[(size_t)row * ldc + col] = v;
                }
            }
        }
    } else {
        // bf16 out: stage in LDS row-major, then coalesced dwordx4 stores
        u16* st = (u16*)smem;   // 128x128 bf16 = 32 KB (overlays sA+sB; safe post-barrier)
#pragma unroll
        for (int mt = 0; mt < 4; mt++) {
#pragma unroll
            for (int r = 0; r < 4; r++) {
                int rl = wr * 64 + mt * 16 + q * 4 + r;
                int rg = m0 + rl;
                float scale = 1.0f;
                if (INVK) scale = 1.0f / kv[rg];
#pragma unroll
                for (int nt = 0; nt < 4; nt++) {
                    int cl = wc * 64 + nt * 16 + lm;
                    int cg = n0 + cl;
                    float v = acc[mt][nt][r];
                    if (BIAS) v += bias[cg];
                    if (ACCIN) {
                        u16 raw = accin[(size_t)rg * ldacc + cg];
                        union { u16 u; bf16 h; } cu; cu.u = raw;
                        v += __bfloat162float(cu.h);
                    }
                    if (INVK) v *= scale;
                    if (cg < relu_ncols) v = fmaxf(v, 0.f);
                    union { u16 u; bf16 h; } ou; ou.h = __float2bfloat16(v);
                    st[rl * 128 + cl] = ou.u;
                }
            }
        }
        __syncthreads();
        u16* Cb = (u16*)Cp;
#pragma unroll
        for (int c = 0; c < 8; c++) {
            int idx = tid + c * 256;              // 0..2047 chunks of 8 bf16
            int rl = idx >> 4, cl = (idx & 15) * 8;
            *(uint4*)(Cb + (size_t)(m0 + rl) * ldc + n0 + cl) = ((const uint4*)st)[idx];
        }
    }
}

// ---------------------------------------------------------------------------
// kfinal: k = clip(sigmoid(kpart+b3)*1024 * sigmoid(ks)*2, 1, 1024)
// ---------------------------------------------------------------------------
__global__ __launch_bounds__(256) void kfinal(
    const float* __restrict__ kpart, const float* __restrict__ b3,
    const float* __restrict__ kscale, float* __restrict__ kout,
    float* __restrict__ scl)
{
    int i = blockIdx.x * 256 + threadIdx.x;
    float z = kpart[i] + b3[0];
    float kk = 1024.0f / (1.0f + expf(-z));
    float sc = 1.0f / (1.0f + expf(-kscale[0]));
    kout[i] = fminf(fmaxf(kk * sc * 2.0f, 1.0f), 1024.0f);
    if (i == 0) scl[0] = 0.0f;
}

// ---------------------------------------------------------------------------
// khot: wave-per-row top-m on bf16 keys, ties by lowest index. 2x8-bit radix,
// per-wave LDS histogram, no __syncthreads. Writes fp32 mask + bf16 mask.
// ---------------------------------------------------------------------------
__device__ inline void suffix_pick(const unsigned* h, int lane, unsigned target,
                                   unsigned& bucket, unsigned& rem)
{
    uint4 hv = *(const uint4*)(h + lane * 4);
    unsigned local = hv.x + hv.y + hv.z + hv.w;
    unsigned incl = local;
#pragma unroll
    for (int off = 1; off < 64; off <<= 1) {
        unsigned t = __shfl_down(incl, off);
        if (lane + off < 64) incl += t;
    }
    unsigned higher = incl - local;
    unsigned s3 = higher + hv.w;
    unsigned s2 = s3 + hv.z;
    unsigned s1 = s2 + hv.y;
    unsigned s0 = s1 + hv.x;
    unsigned suf[5] = {s0, s1, s2, s3, higher};
    int bj = -1; unsigned rm = 0;
#pragma unroll
    for (int j = 0; j < 4; j++)
        if (suf[j] >= target && suf[j + 1] < target) { bj = j; rm = target - suf[j + 1]; }
    unsigned long long mk = __ballot(bj >= 0);
    int src = (int)__ffsll((unsigned long long)mk) - 1;
    bucket = __shfl((unsigned)(lane * 4 + bj), src);
    rem    = __shfl(rm, src);
}

__global__ __launch_bounds__(256) void khot_kernel(
    u16* __restrict__ lb, const float* __restrict__ kvals,
    float* __restrict__ mf)
{
    __shared__ unsigned hist[4][256];
    const int w = threadIdx.x >> 6, lane = threadIdx.x & 63;
    const int row = blockIdx.x * 4 + w;
    u16* rp = lb + (size_t)row * QDIM;
    float* mfp = mf + (size_t)row * QDIM;

    u16x8 v0 = *(const u16x8*)(rp + lane * 8);
    u16x8 v1 = *(const u16x8*)(rp + 512 + lane * 8);
    unsigned key[2][8];
#pragma unroll
    for (int j = 0; j < 8; j++) {
        unsigned a = v0[j], b = v1[j];
        key[0][j] = (a & 0x8000u) ? (~a & 0xffffu) : (a | 0x8000u);
        key[1][j] = (b & 0x8000u) ? (~b & 0xffffu) : (b | 0x8000u);
    }
    int mi = (int)ceilf(kvals[row]);
    mi = mi < 1 ? 1 : (mi > QDIM ? QDIM : mi);
    const unsigned m = (unsigned)mi;
    unsigned* h = hist[w];

    *(uint4*)(h + lane * 4) = make_uint4(0, 0, 0, 0);
    __threadfence_block();
#pragma unroll
    for (int c = 0; c < 2; c++)
#pragma unroll
        for (int j = 0; j < 8; j++)
            atomicAdd(&h[key[c][j] >> 8], 1u);
    __threadfence_block();
    unsigned hi, rem1;
    suffix_pick(h, lane, m, hi, rem1);

    *(uint4*)(h + lane * 4) = make_uint4(0, 0, 0, 0);
    __threadfence_block();
#pragma unroll
    for (int c = 0; c < 2; c++)
#pragma unroll
        for (int j = 0; j < 8; j++)
            if ((key[c][j] >> 8) == hi) atomicAdd(&h[key[c][j] & 255u], 1u);
    __threadfence_block();
    unsigned lo, need;
    suffix_pick(h, lane, rem1, lo, need);

    const unsigned um = (hi << 8) | lo;

    unsigned cnt0 = 0, cnt1 = 0;
#pragma unroll
    for (int j = 0; j < 8; j++) { cnt0 += (key[0][j] == um); cnt1 += (key[1][j] == um); }
    unsigned pack = cnt0 | (cnt1 << 16);
    unsigned incl = pack;
#pragma unroll
    for (int off = 1; off < 64; off <<= 1) {
        unsigned t = __shfl_up(incl, off);
        if (lane >= off) incl += t;
    }
    unsigned excl = incl - pack;
    unsigned tot0 = __shfl(incl, 63) & 0xffffu;
    unsigned r0 = excl & 0xffffu;
    unsigned r1 = tot0 + (excl >> 16);

    float of[2][8];
    u16x8 mb0, mb1;
#pragma unroll
    for (int j = 0; j < 8; j++) {
        unsigned kv_ = key[0][j];
        bool s;
        if (kv_ > um) s = true;
        else if (kv_ == um) { s = (r0 < need); r0++; }
        else s = false;
        of[0][j] = s ? 1.0f : 0.0f;
        mb0[j] = s ? (u16)0x3F80 : (u16)0;
    }
#pragma unroll
    for (int j = 0; j < 8; j++) {
        unsigned kv_ = key[1][j];
        bool s;
        if (kv_ > um) s = true;
        else if (kv_ == um) { s = (r1 < need); r1++; }
        else s = false;
        of[1][j] = s ? 1.0f : 0.0f;
        mb1[j] = s ? (u16)0x3F80 : (u16)0;
    }
    *(float4*)(mfp + lane * 8)           = make_float4(of[0][0], of[0][1], of[0][2], of[0][3]);
    *(float4*)(mfp + lane * 8 + 4)       = make_float4(of[0][4], of[0][5], of[0][6], of[0][7]);
    *(float4*)(mfp + 512 + lane * 8)     = make_float4(of[1][0], of[1][1], of[1][2], of[1][3]);
    *(float4*)(mfp + 512 + lane * 8 + 4) = make_float4(of[1][4], of[1][5], of[1][6], of[1][7]);
    *(u16x8*)(rp + lane * 8)       = mb0;
    *(u16x8*)(rp + 512 + lane * 8) = mb1;
}

// ---------------------------------------------------------------------------
extern "C" void kernel_launch(void* const* d_in, const int* in_sizes, int n_in,
                              void* d_out, int out_size, void* d_ws, size_t ws_size,
                              hipStream_t stream) {
    const float* x     = (const float*)d_in[0];
    const float* W_e1  = (const float*)d_in[1];
    const float* b_e1  = (const float*)d_in[2];
    const float* W_e2  = (const float*)d_in[3];
    const float* b_e2  = (const float*)d_in[4];
    const float* W_cb  = (const float*)d_in[5];
    const float* W_d1  = (const float*)d_in[6];
    const float* b_d1  = (const float*)d_in[7];
    const float* W_d2  = (const float*)d_in[8];
    const float* b_d2  = (const float*)d_in[9];
    const float* W_k1  = (const float*)d_in[10];
    const float* b_k1  = (const float*)d_in[11];
    const float* W_k2  = (const float*)d_in[12];
    const float* b_k2  = (const float*)d_in[13];
    const float* W_k3  = (const float*)d_in[14];
    const float* b_k3  = (const float*)d_in[15];
    const float* k_scl = (const float*)d_in[16];

    float* out   = (float*)d_out;
    float* recon = out;
    float* maskf = out + OUT_KHOT_OFF;
    float* scl   = out + OUT_SCALAR_OFF;
    float* kout  = out + OUT_K_OFF;

    char* ws = (char*)d_ws;
    bf16* wb_k1 = (bf16*)(ws + WS_WK1);
    bf16* wb_e2 = (bf16*)(ws + WS_WE2);
    bf16* wb_cb = (bf16*)(ws + WS_WCB);
    bf16* wb_d1 = (bf16*)(ws + WS_WD1);
    bf16* wb_d2 = (bf16*)(ws + WS_WD2);
    bf16* wb_k2 = (bf16*)(ws + WS_WK2);
    bf16* wstk  = (bf16*)(ws + WS_WSTK);
    float* bstk = (float*)(ws + WS_BSTK);
    float* kpart = (float*)(ws + WS_KPART);
    bf16* bufA  = (bf16*)(ws + WS_BUFA);   // [h1 | kp1] 32768x1024; later q (ldc 256)
    bf16* bufB  = (bf16*)(ws + WS_BUFB);   // logits -> bf16 mask, 32768x1024
    bf16* bufC  = (bf16*)(ws + WS_BUFC);   // hk1 -> hd1, 32768x512

    hipMemsetAsync(kpart, 0, Bn * sizeof(float), stream);

    // all weight conversions + stacked weight/bias in one launch
    cvt_kernel<<<dim3(2177), dim3(256), 0, stream>>>(
        W_e1, W_e2, W_cb, W_d1, W_d2, W_k1, W_k2, b_e1, ws);

    const dim3 blk(256);
    const int FULL = 1 << 30;

    // E1||K1a: [h1 | kp1] = x @ [We1;Wk1a]^T + [b_e1|0]; relu on cols<512 only
    mgemm<1, 0, 1, 0, 0><<<dim3(8, Bn / 128), blk, 0, stream>>>(
        x, nullptr, wstk, bstk, nullptr, bufA, 1024, 256, 256, 256, 1024, 0, 512);
    // E2: logits = h1 @ We2^T + b_e2 -> bufB (bf16)
    mgemm<0, 0, 1, 0, 0><<<dim3(8, Bn / 128), blk, 0, stream>>>(
        bufA, nullptr, wb_e2, b_e2, nullptr, bufB, 1024, 512, 1024, 512, 1024, 0, 0);
    // K1b: hk1 = relu(logits @ Wk1[:,256:]^T + kp1 + b_k1) -> bufC
    mgemm<0, 0, 1, 0, 1><<<dim3(4, Bn / 128), blk, 0, stream>>>(
        bufB, (const u16*)bufA + 512, wb_k1 + 256, b_k1, nullptr, bufC,
        512, 1024, 1024, 1280, 512, 1024, FULL);
    // K2+kdot: kpart[row] += relu(hk1 @ Wk2^T + b_k2) . w3
    mgemm<0, 2, 1, 0, 0><<<dim3(4, Bn / 128), blk, 0, stream>>>(
        bufC, nullptr, wb_k2, b_k2, W_k3, kpart, 512, 512, 512, 512, 512, 0, FULL);
    // k = clip(sigmoid(kpart + b3)*1024 * sigmoid(ks)*2, 1, 1024)
    kfinal<<<dim3(Bn / 256), blk, 0, stream>>>(kpart, b_k3, k_scl, kout, scl);
    // khot: logits (bufB) -> fp32 mask (d_out) + bf16 mask (bufB in place)
    khot_kernel<<<dim3(Bn / 4), blk, 0, stream>>>((u16*)bufB, kout, maskf);
    // CB: q = (mask/k) @ Wcb^T -> bufA (ldc 256; [h1|kp1] dead)
    mgemm<0, 0, 0, 1, 0><<<dim3(2, Bn / 128), blk, 0, stream>>>(
        bufB, nullptr, wb_cb, nullptr, kout, bufA, 256, 1024, 1024, 1024, 256, 0, 0);
    // D1: hd1 = relu(q @ Wd1^T + b_d1) -> bufC (hk1 dead)
    mgemm<0, 0, 1, 0, 0><<<dim3(4, Bn / 128), blk, 0, stream>>>(
        bufA, nullptr, wb_d1, b_d1, nullptr, bufC, 512, 256, 256, 256, 512, 0, FULL);
    // D2: recon = hd1 @ Wd2^T + b_d2 -> d_out (fp32)
    mgemm<0, 1, 1, 0, 0><<<dim3(2, Bn / 128), blk, 0, stream>>>(
        bufC, nullptr, wb_d2, b_d2, nullptr, recon, 256, 512, 512, 512, 256, 0, 0);
}

// Round 5
// 538.614 us; speedup vs baseline: 6.4935x; 1.0014x over previous
//
#include <hip/hip_runtime.h>
#include <hip/hip_bf16.h>
#include <math.h>

typedef __hip_bfloat16 bf16;
typedef unsigned short u16;
using frag8 = __attribute__((ext_vector_type(8))) short;   // 8 bf16 = 4 VGPRs
using f32x4 = __attribute__((ext_vector_type(4))) float;   // MFMA accumulator
using u16x8 = __attribute__((ext_vector_type(8))) unsigned short;

// Problem constants
#define Bn      32768
#define IN_DIM  256
#define N_HDIM  512
#define QDIM    1024
#define N_EMBD  256

// Output layout (float32): recon [B*256] | khot [B*1024] | scalar [1] | k [B]
#define OUT_KHOT_OFF   ((size_t)Bn * IN_DIM)
#define OUT_SCALAR_OFF (OUT_KHOT_OFF + (size_t)Bn * QDIM)
#define OUT_K_OFF      (OUT_SCALAR_OFF + 1)

// Workspace layout (bytes)
#define WS_WK1    0                                   // 512x1280 bf16 (full)
#define WS_WE2    (WS_WK1 + 512*1280*2)               // 1024x512
#define WS_WCB    (WS_WE2 + 1024*512*2)               // 256x1024
#define WS_WD1    (WS_WCB + 256*1024*2)               // 512x256
#define WS_WD2    (WS_WD1 + 512*256*2)                // 256x512
#define WS_WK2    (WS_WD2 + 256*512*2)                // 512x512
#define WS_WSTK   (WS_WK2 + 512*512*2)                // 1024x256 [We1 ; Wk1[:,:256]]
#define WS_BSTK   (WS_WSTK + 1024*256*2)              // 1024 fp32 [b_e1 | 0]
#define WS_KPART  (WS_BSTK + 1024*4)                  // Bn fp32 (zeroed by cvt)
#define WS_BUFA   (WS_KPART + (size_t)Bn*4)           // Bn x 1024 bf16: [h1|kp1] -> q
#define WS_BUFB   (WS_BUFA + (size_t)Bn*1024*2)       // Bn x 1024 bf16: logits -> mask
#define WS_BUFC   (WS_BUFB + (size_t)Bn*1024*2)       // Bn x 512 bf16: hk1 -> hd1
#define WS_WE2T   (WS_BUFC + (size_t)Bn*512*2)        // 512x1024 bf16 (We2 transposed)
#define WS_WCOMB2 (WS_WE2T + 512*1024*2)              // 512x512 bf16 (Wk1b @ We2)
#define WS_BCONST (WS_WCOMB2 + 512*512*2)             // 512 fp32
// total ~174 MB (ws_size ~672 MB per fill counters)

// cvt grid segmentation
#define CVT_BASE  2177       // weight f32->bf16 conversions + stacked W/bias
#define CVT_T     512        // We2 transpose
#define CVT_BC    128        // bconst GEMV (4 waves/block, 512 rows)
#define CVT_KZ    32         // kpart zeroing
#define CVT_GRID  (CVT_BASE + CVT_T + CVT_BC + CVT_KZ)   // 2849

__device__ inline void async_copy16(const void* g, void* l) {
    __builtin_amdgcn_global_load_lds(
        (const __attribute__((address_space(1))) void*)g,
        (__attribute__((address_space(3))) void*)l, 16, 0, 0);
}

__device__ inline void cv4(bf16* d, float4 v) {
    union { short4 s; bf16 h[4]; } u;
    u.h[0] = __float2bfloat16(v.x); u.h[1] = __float2bfloat16(v.y);
    u.h[2] = __float2bfloat16(v.z); u.h[3] = __float2bfloat16(v.w);
    *(short4*)d = u.s;
}

// ---------------------------------------------------------------------------
// One-shot prep: all weight bf16 conversions, stacked [We1;Wk1a] + bias,
// We2 transpose, bconst = Wk1b . b_e2 + b_k1, kpart zeroing.
// ---------------------------------------------------------------------------
__global__ __launch_bounds__(256) void cvt_kernel(
    const float* __restrict__ We1, const float* __restrict__ We2,
    const float* __restrict__ Wcb, const float* __restrict__ Wd1,
    const float* __restrict__ Wd2, const float* __restrict__ Wk1,
    const float* __restrict__ Wk2, const float* __restrict__ be1,
    const float* __restrict__ be2, const float* __restrict__ bk1,
    char* __restrict__ ws)
{
    const int bx = blockIdx.x, tid = threadIdx.x;
    if (bx < CVT_BASE) {
        int id = bx * 256 + tid;
        const float* src; bf16* dst; int off;
        if      (id < 163840) { src = Wk1; dst = (bf16*)(ws + WS_WK1); off = id; }
        else if (id < 294912) { src = We2; dst = (bf16*)(ws + WS_WE2); off = id - 163840; }
        else if (id < 360448) { src = Wcb; dst = (bf16*)(ws + WS_WCB); off = id - 294912; }
        else if (id < 393216) { src = Wd1; dst = (bf16*)(ws + WS_WD1); off = id - 360448; }
        else if (id < 425984) { src = Wd2; dst = (bf16*)(ws + WS_WD2); off = id - 393216; }
        else if (id < 491520) { src = Wk2; dst = (bf16*)(ws + WS_WK2); off = id - 425984; }
        else if (id < 524288) { src = We1; dst = (bf16*)(ws + WS_WSTK); off = id - 491520; }
        else if (id < 557056) {           // Wk1[:, :256] -> wstk rows 512..1023
            int l = id - 524288; int r = l >> 6, c4 = (l & 63) * 4;
            float4 v = *(const float4*)(Wk1 + (size_t)r * 1280 + c4);
            cv4((bf16*)(ws + WS_WSTK) + 131072 + r * 256 + c4, v);
            return;
        } else {                           // bias_stk: [b_e1 | zeros], fp32
            int l = id - 557056;
            float4 v = (l < 128) ? *(const float4*)(be1 + l * 4)
                                 : make_float4(0.f, 0.f, 0.f, 0.f);
            *(float4*)((float*)(ws + WS_BSTK) + l * 4) = v;
            return;
        }
        float4 v = *(const float4*)(src + (size_t)off * 4);
        cv4(dst + (size_t)off * 4, v);
    } else if (bx < CVT_BASE + CVT_T) {
        // We2T[n][k] = We2[k][n]; n=0..511, k in groups of 4
        int local = (bx - CVT_BASE) * 256 + tid;      // 0..131071
        int n = local & 511;
        int k = (local >> 9) * 4;
        float4 v;
        v.x = We2[(size_t)(k + 0) * 512 + n];
        v.y = We2[(size_t)(k + 1) * 512 + n];
        v.z = We2[(size_t)(k + 2) * 512 + n];
        v.w = We2[(size_t)(k + 3) * 512 + n];
        cv4((bf16*)(ws + WS_WE2T) + (size_t)n * 1024 + k, v);
    } else if (bx < CVT_BASE + CVT_T + CVT_BC) {
        // bconst[r] = sum_k Wk1[r][256+k] * be2[k] + bk1[r]
        int r = (bx - CVT_BASE - CVT_T) * 4 + (tid >> 6);
        int lane = tid & 63;
        const float* wr = Wk1 + (size_t)r * 1280 + 256;
        float s = 0.f;
#pragma unroll
        for (int t = 0; t < 16; t++) {
            int j = lane + t * 64;
            s = fmaf(wr[j], be2[j], s);
        }
#pragma unroll
        for (int off = 32; off > 0; off >>= 1) s += __shfl_down(s, off);
        if (lane == 0) ((float*)(ws + WS_BCONST))[r] = s + bk1[r];
    } else {
        // zero kpart
        int idx = ((bx - CVT_BASE - CVT_T - CVT_BC) * 256 + tid) * 4;
        *(float4*)((float*)(ws + WS_KPART) + idx) = make_float4(0.f, 0.f, 0.f, 0.f);
    }
}

// ---------------------------------------------------------------------------
// bf16 MFMA GEMM: 128x128 tile, BK=64, 4 waves (2x2), 16x16x32 MFMA.
// XOR-swizzled LDS staging; coalesced bf16 epilogue via LDS transpose.
// ASRC: 0 = A bf16 (global_load_lds); 1 = A fp32 (convert-stage).
// OMODE: 0 = bf16 C (coalesced); 1 = fp32 C; 2 = kdot epilogue (atomicAdd).
// relu_ncols (runtime): relu applied iff global col < relu_ncols.
// ACCIN: epilogue adds bf16 accin[row*ldacc + col] before relu.
// ---------------------------------------------------------------------------
template<int ASRC, int OMODE, int BIAS, int INVK, int ACCIN>
__global__ __launch_bounds__(256) void mgemm(
    const void* __restrict__ Ap, const u16* __restrict__ accin,
    const bf16* __restrict__ W, const float* __restrict__ bias,
    const float* __restrict__ kv, void* __restrict__ Cp,
    int N, int K, int lda, int ldw, int ldc, int ldacc, int relu_ncols)
{
    __shared__ __align__(16) char smem[32768];
    bf16* sA = (bf16*)smem;
    bf16* sB = (bf16*)(smem + 16384);

    const int tid = threadIdx.x;
    const int wv = tid >> 6, ln = tid & 63;
    const int wr = wv >> 1, wc = wv & 1;
    const int m0 = blockIdx.y * 128;
    const int n0 = blockIdx.x * 128;
    const int lm = ln & 15, q = ln >> 4;

    f32x4 acc[4][4];
#pragma unroll
    for (int i = 0; i < 4; i++)
#pragma unroll
        for (int j = 0; j < 4; j++)
            acc[i][j] = (f32x4){0.f, 0.f, 0.f, 0.f};

    for (int k0 = 0; k0 < K; k0 += 64) {
        if (ASRC == 0) {
            const bf16* A = (const bf16*)Ap;
#pragma unroll
            for (int i = 0; i < 4; i++) {
                int c = wv * 256 + i * 64 + ln;
                int row = c >> 3;
                int g = (c & 7) ^ (row & 7);
                async_copy16(A + (size_t)(m0 + row) * lda + k0 + g * 8, &sA[c * 8]);
            }
        } else {
            const float* Af = (const float*)Ap;
#pragma unroll
            for (int i = 0; i < 4; i++) {
                int c = wv * 256 + i * 64 + ln;
                int row = c >> 3;
                int g = (c & 7) ^ (row & 7);
                const float* src = Af + (size_t)(m0 + row) * lda + k0 + g * 8;
                float4 v0 = *(const float4*)src;
                float4 v1 = *(const float4*)(src + 4);
                union { frag8 s; bf16 h[8]; } u;
                u.h[0] = __float2bfloat16(v0.x); u.h[1] = __float2bfloat16(v0.y);
                u.h[2] = __float2bfloat16(v0.z); u.h[3] = __float2bfloat16(v0.w);
                u.h[4] = __float2bfloat16(v1.x); u.h[5] = __float2bfloat16(v1.y);
                u.h[6] = __float2bfloat16(v1.z); u.h[7] = __float2bfloat16(v1.w);
                *(frag8*)(&sA[c * 8]) = u.s;
            }
        }
#pragma unroll
        for (int i = 0; i < 4; i++) {
            int c = wv * 256 + i * 64 + ln;
            int row = c >> 3;
            int g = (c & 7) ^ (row & 7);
            async_copy16(W + (size_t)(n0 + row) * ldw + k0 + g * 8, &sB[c * 8]);
        }
        __syncthreads();

#pragma unroll
        for (int kk = 0; kk < 2; kk++) {
            frag8 af[4], bfr[4];
#pragma unroll
            for (int t = 0; t < 4; t++) {
                int r = wr * 64 + t * 16 + lm;
                af[t] = *(const frag8*)&sA[r * 64 + (((kk * 4 + q) ^ (r & 7)) * 8)];
                int n = wc * 64 + t * 16 + lm;
                bfr[t] = *(const frag8*)&sB[n * 64 + (((kk * 4 + q) ^ (n & 7)) * 8)];
            }
#pragma unroll
            for (int mt = 0; mt < 4; mt++)
#pragma unroll
                for (int nt = 0; nt < 4; nt++)
                    acc[mt][nt] = __builtin_amdgcn_mfma_f32_16x16x32_bf16(
                        af[mt], bfr[nt], acc[mt][nt], 0, 0, 0);
        }
        __syncthreads();
    }

    // ---- epilogue (C frag layout: col=lane&15, row=(lane>>4)*4+reg) ----
    if (OMODE == 2) {
        float* kpart = (float*)Cp;
#pragma unroll
        for (int mt = 0; mt < 4; mt++) {
#pragma unroll
            for (int r = 0; r < 4; r++) {
                int row = m0 + wr * 64 + mt * 16 + q * 4 + r;
                float s = 0.f;
#pragma unroll
                for (int nt = 0; nt < 4; nt++) {
                    int col = n0 + wc * 64 + nt * 16 + lm;
                    float v = acc[mt][nt][r] + bias[col];
                    v = fmaxf(v, 0.f);
                    s = fmaf(v, kv[col], s);
                }
#pragma unroll
                for (int off = 8; off > 0; off >>= 1) s += __shfl_down(s, off);
                if (lm == 0) atomicAdd(&kpart[row], s);
            }
        }
    } else if (OMODE == 1) {
#pragma unroll
        for (int mt = 0; mt < 4; mt++) {
#pragma unroll
            for (int r = 0; r < 4; r++) {
                int row = m0 + wr * 64 + mt * 16 + q * 4 + r;
#pragma unroll
                for (int nt = 0; nt < 4; nt++) {
                    int col = n0 + wc * 64 + nt * 16 + lm;
                    float v = acc[mt][nt][r];
                    if (BIAS) v += bias[col];
                    if (col < relu_ncols) v = fmaxf(v, 0.f);
                    ((float*)Cp)[(size_t)row * ldc + col] = v;
                }
            }
        }
    } else {
        u16* st = (u16*)smem;   // 128x128 bf16 = 32 KB (post-barrier overlay)
#pragma unroll
        for (int mt = 0; mt < 4; mt++) {
#pragma unroll
            for (int r = 0; r < 4; r++) {
                int rl = wr * 64 + mt * 16 + q * 4 + r;
                int rg = m0 + rl;
                float scale = 1.0f;
                if (INVK) scale = 1.0f / kv[rg];
#pragma unroll
                for (int nt = 0; nt < 4; nt++) {
                    int cl = wc * 64 + nt * 16 + lm;
                    int cg = n0 + cl;
                    float v = acc[mt][nt][r];
                    if (BIAS) v += bias[cg];
                    if (ACCIN) {
                        u16 raw = accin[(size_t)rg * ldacc + cg];
                        union { u16 u; bf16 h; } cu; cu.u = raw;
                        v += __bfloat162float(cu.h);
                    }
                    if (INVK) v *= scale;
                    if (cg < relu_ncols) v = fmaxf(v, 0.f);
                    union { u16 u; bf16 h; } ou; ou.h = __float2bfloat16(v);
                    st[rl * 128 + cl] = ou.u;
                }
            }
        }
        __syncthreads();
        u16* Cb = (u16*)Cp;
#pragma unroll
        for (int c = 0; c < 8; c++) {
            int idx = tid + c * 256;
            int rl = idx >> 4, cl = (idx & 15) * 8;
            *(uint4*)(Cb + (size_t)(m0 + rl) * ldc + n0 + cl) = ((const uint4*)st)[idx];
        }
    }
}

// ---------------------------------------------------------------------------
// khot + kfinal fused: wave-per-row. Computes k from kpart, writes kout/scl,
// then top-m mask on bf16 keys (2x8-bit radix, per-wave LDS histogram,
// no __syncthreads). Writes fp32 mask (d_out) + bf16 mask (in place).
// ---------------------------------------------------------------------------
__device__ inline void suffix_pick(const unsigned* h, int lane, unsigned target,
                                   unsigned& bucket, unsigned& rem)
{
    uint4 hv = *(const uint4*)(h + lane * 4);
    unsigned local = hv.x + hv.y + hv.z + hv.w;
    unsigned incl = local;
#pragma unroll
    for (int off = 1; off < 64; off <<= 1) {
        unsigned t = __shfl_down(incl, off);
        if (lane + off < 64) incl += t;
    }
    unsigned higher = incl - local;
    unsigned s3 = higher + hv.w;
    unsigned s2 = s3 + hv.z;
    unsigned s1 = s2 + hv.y;
    unsigned s0 = s1 + hv.x;
    unsigned suf[5] = {s0, s1, s2, s3, higher};
    int bj = -1; unsigned rm = 0;
#pragma unroll
    for (int j = 0; j < 4; j++)
        if (suf[j] >= target && suf[j + 1] < target) { bj = j; rm = target - suf[j + 1]; }
    unsigned long long mk = __ballot(bj >= 0);
    int src = (int)__ffsll((unsigned long long)mk) - 1;
    bucket = __shfl((unsigned)(lane * 4 + bj), src);
    rem    = __shfl(rm, src);
}

__global__ __launch_bounds__(256) void khot_kernel(
    u16* __restrict__ lb, const float* __restrict__ kpart,
    const float* __restrict__ b3, const float* __restrict__ kscale,
    float* __restrict__ mf, float* __restrict__ kout, float* __restrict__ scl)
{
    __shared__ unsigned hist[4][256];
    const int w = threadIdx.x >> 6, lane = threadIdx.x & 63;
    const int row = blockIdx.x * 4 + w;
    u16* rp = lb + (size_t)row * QDIM;
    float* mfp = mf + (size_t)row * QDIM;

    // k for this row (all lanes compute; lane 0 stores)
    float z = kpart[row] + b3[0];
    float kk = 1024.0f / (1.0f + expf(-z));
    float sc = 1.0f / (1.0f + expf(-kscale[0]));
    float kvv = fminf(fmaxf(kk * sc * 2.0f, 1.0f), 1024.0f);
    if (lane == 0) kout[row] = kvv;
    if (row == 0 && lane == 0) scl[0] = 0.0f;

    u16x8 v0 = *(const u16x8*)(rp + lane * 8);
    u16x8 v1 = *(const u16x8*)(rp + 512 + lane * 8);
    unsigned key[2][8];
#pragma unroll
    for (int j = 0; j < 8; j++) {
        unsigned a = v0[j], b = v1[j];
        key[0][j] = (a & 0x8000u) ? (~a & 0xffffu) : (a | 0x8000u);
        key[1][j] = (b & 0x8000u) ? (~b & 0xffffu) : (b | 0x8000u);
    }
    int mi = (int)ceilf(kvv);
    mi = mi < 1 ? 1 : (mi > QDIM ? QDIM : mi);
    const unsigned m = (unsigned)mi;
    unsigned* h = hist[w];

    *(uint4*)(h + lane * 4) = make_uint4(0, 0, 0, 0);
    __threadfence_block();
#pragma unroll
    for (int c = 0; c < 2; c++)
#pragma unroll
        for (int j = 0; j < 8; j++)
            atomicAdd(&h[key[c][j] >> 8], 1u);
    __threadfence_block();
    unsigned hi, rem1;
    suffix_pick(h, lane, m, hi, rem1);

    *(uint4*)(h + lane * 4) = make_uint4(0, 0, 0, 0);
    __threadfence_block();
#pragma unroll
    for (int c = 0; c < 2; c++)
#pragma unroll
        for (int j = 0; j < 8; j++)
            if ((key[c][j] >> 8) == hi) atomicAdd(&h[key[c][j] & 255u], 1u);
    __threadfence_block();
    unsigned lo, need;
    suffix_pick(h, lane, rem1, lo, need);

    const unsigned um = (hi << 8) | lo;

    unsigned cnt0 = 0, cnt1 = 0;
#pragma unroll
    for (int j = 0; j < 8; j++) { cnt0 += (key[0][j] == um); cnt1 += (key[1][j] == um); }
    unsigned pack = cnt0 | (cnt1 << 16);
    unsigned incl = pack;
#pragma unroll
    for (int off = 1; off < 64; off <<= 1) {
        unsigned t = __shfl_up(incl, off);
        if (lane >= off) incl += t;
    }
    unsigned excl = incl - pack;
    unsigned tot0 = __shfl(incl, 63) & 0xffffu;
    unsigned r0 = excl & 0xffffu;
    unsigned r1 = tot0 + (excl >> 16);

    float of[2][8];
    u16x8 mb0, mb1;
#pragma unroll
    for (int j = 0; j < 8; j++) {
        unsigned kv_ = key[0][j];
        bool s;
        if (kv_ > um) s = true;
        else if (kv_ == um) { s = (r0 < need); r0++; }
        else s = false;
        of[0][j] = s ? 1.0f : 0.0f;
        mb0[j] = s ? (u16)0x3F80 : (u16)0;
    }
#pragma unroll
    for (int j = 0; j < 8; j++) {
        unsigned kv_ = key[1][j];
        bool s;
        if (kv_ > um) s = true;
        else if (kv_ == um) { s = (r1 < need); r1++; }
        else s = false;
        of[1][j] = s ? 1.0f : 0.0f;
        mb1[j] = s ? (u16)0x3F80 : (u16)0;
    }
    *(float4*)(mfp + lane * 8)           = make_float4(of[0][0], of[0][1], of[0][2], of[0][3]);
    *(float4*)(mfp + lane * 8 + 4)       = make_float4(of[0][4], of[0][5], of[0][6], of[0][7]);
    *(float4*)(mfp + 512 + lane * 8)     = make_float4(of[1][0], of[1][1], of[1][2], of[1][3]);
    *(float4*)(mfp + 512 + lane * 8 + 4) = make_float4(of[1][4], of[1][5], of[1][6], of[1][7]);
    *(u16x8*)(rp + lane * 8)       = mb0;
    *(u16x8*)(rp + 512 + lane * 8) = mb1;
}

// ---------------------------------------------------------------------------
extern "C" void kernel_launch(void* const* d_in, const int* in_sizes, int n_in,
                              void* d_out, int out_size, void* d_ws, size_t ws_size,
                              hipStream_t stream) {
    const float* x     = (const float*)d_in[0];
    const float* W_e1  = (const float*)d_in[1];
    const float* b_e1  = (const float*)d_in[2];
    const float* W_e2  = (const float*)d_in[3];
    const float* b_e2  = (const float*)d_in[4];
    const float* W_cb  = (const float*)d_in[5];
    const float* W_d1  = (const float*)d_in[6];
    const float* b_d1  = (const float*)d_in[7];
    const float* W_d2  = (const float*)d_in[8];
    const float* b_d2  = (const float*)d_in[9];
    const float* W_k1  = (const float*)d_in[10];
    const float* b_k1  = (const float*)d_in[11];
    const float* W_k2  = (const float*)d_in[12];
    const float* b_k2  = (const float*)d_in[13];
    const float* W_k3  = (const float*)d_in[14];
    const float* b_k3  = (const float*)d_in[15];
    const float* k_scl = (const float*)d_in[16];

    float* out   = (float*)d_out;
    float* recon = out;
    float* maskf = out + OUT_KHOT_OFF;
    float* scl   = out + OUT_SCALAR_OFF;
    float* kout  = out + OUT_K_OFF;

    char* ws = (char*)d_ws;
    bf16* wb_k1  = (bf16*)(ws + WS_WK1);
    bf16* wb_e2  = (bf16*)(ws + WS_WE2);
    bf16* wb_cb  = (bf16*)(ws + WS_WCB);
    bf16* wb_d1  = (bf16*)(ws + WS_WD1);
    bf16* wb_d2  = (bf16*)(ws + WS_WD2);
    bf16* wb_k2  = (bf16*)(ws + WS_WK2);
    bf16* wstk   = (bf16*)(ws + WS_WSTK);
    float* bstk  = (float*)(ws + WS_BSTK);
    float* kpart = (float*)(ws + WS_KPART);
    bf16* bufA   = (bf16*)(ws + WS_BUFA);   // [h1 | kp1] 32768x1024; later q (ldc 256)
    bf16* bufB   = (bf16*)(ws + WS_BUFB);   // logits -> bf16 mask, 32768x1024
    bf16* bufC   = (bf16*)(ws + WS_BUFC);   // hk1 -> hd1, 32768x512
    bf16* we2t   = (bf16*)(ws + WS_WE2T);
    bf16* wcomb2 = (bf16*)(ws + WS_WCOMB2);
    float* bconst = (float*)(ws + WS_BCONST);

    const dim3 blk(256);
    const int FULL = 1 << 30;

    // prep: conversions + stacked W/b + We2T + bconst + kpart zero (1 launch)
    cvt_kernel<<<dim3(CVT_GRID), blk, 0, stream>>>(
        W_e1, W_e2, W_cb, W_d1, W_d2, W_k1, W_k2, b_e1, b_e2, b_k1, ws);

    // Wcomb2 = Wk1b @ We2  (M=512, N=512, K=1024) -> bf16
    mgemm<0, 0, 0, 0, 0><<<dim3(4, 4), blk, 0, stream>>>(
        wb_k1 + 256, nullptr, we2t, nullptr, nullptr, wcomb2,
        512, 1024, 1280, 1024, 512, 0, 0);

    // E1||K1a: [h1 | kp1] = x @ [We1;Wk1a]^T + [b_e1|0]; relu cols<512 only
    mgemm<1, 0, 1, 0, 0><<<dim3(8, Bn / 128), blk, 0, stream>>>(
        x, nullptr, wstk, bstk, nullptr, bufA, 1024, 256, 256, 256, 1024, 0, 512);
    // K1b': hk1 = relu(h1 @ Wcomb2^T + kp1 + bconst) -> bufC   (K=512!)
    mgemm<0, 0, 1, 0, 1><<<dim3(4, Bn / 128), blk, 0, stream>>>(
        bufA, (const u16*)bufA + 512, wcomb2, bconst, nullptr, bufC,
        512, 512, 1024, 512, 512, 1024, FULL);
    // K2+kdot: kpart[row] += relu(hk1 @ Wk2^T + b_k2) . w3
    mgemm<0, 2, 1, 0, 0><<<dim3(4, Bn / 128), blk, 0, stream>>>(
        bufC, nullptr, wb_k2, b_k2, W_k3, kpart, 512, 512, 512, 512, 512, 0, FULL);
    // E2: logits = h1 @ We2^T + b_e2 -> bufB (bf16; only khot consumes)
    mgemm<0, 0, 1, 0, 0><<<dim3(8, Bn / 128), blk, 0, stream>>>(
        bufA, nullptr, wb_e2, b_e2, nullptr, bufB, 1024, 512, 1024, 512, 1024, 0, 0);
    // khot (+kfinal): logits -> fp32 mask (d_out) + bf16 mask; k -> kout/scl
    khot_kernel<<<dim3(Bn / 4), blk, 0, stream>>>(
        (u16*)bufB, kpart, b_k3, k_scl, maskf, kout, scl);
    // CB: q = (mask/k) @ Wcb^T -> bufA (ldc 256; [h1|kp1] dead)
    mgemm<0, 0, 0, 1, 0><<<dim3(2, Bn / 128), blk, 0, stream>>>(
        bufB, nullptr, wb_cb, nullptr, kout, bufA, 256, 1024, 1024, 1024, 256, 0, 0);
    // D1: hd1 = relu(q @ Wd1^T + b_d1) -> bufC
    mgemm<0, 0, 1, 0, 0><<<dim3(4, Bn / 128), blk, 0, stream>>>(
        bufA, nullptr, wb_d1, b_d1, nullptr, bufC, 512, 256, 256, 256, 512, 0, FULL);
    // D2: recon = hd1 @ Wd2^T + b_d2 -> d_out (fp32)
    mgemm<0, 1, 1, 0, 0><<<dim3(2, Bn / 128), blk, 0, stream>>>(
        bufC, nullptr, wb_d2, b_d2, nullptr, recon, 256, 512, 512, 512, 256, 0, 0);
}

// Round 6
// 521.873 us; speedup vs baseline: 6.7018x; 1.0321x over previous
//
#include <hip/hip_runtime.h>
#include <hip/hip_bf16.h>
#include <math.h>

typedef __hip_bfloat16 bf16;
typedef unsigned short u16;
using frag8 = __attribute__((ext_vector_type(8))) short;   // 8 bf16 = 4 VGPRs
using f32x4 = __attribute__((ext_vector_type(4))) float;   // MFMA accumulator
using u16x8 = __attribute__((ext_vector_type(8))) unsigned short;

// Problem constants
#define Bn      32768
#define IN_DIM  256
#define N_HDIM  512
#define QDIM    1024
#define N_EMBD  256

// Output layout (float32): recon [B*256] | khot [B*1024] | scalar [1] | k [B]
#define OUT_KHOT_OFF   ((size_t)Bn * IN_DIM)
#define OUT_SCALAR_OFF (OUT_KHOT_OFF + (size_t)Bn * QDIM)
#define OUT_K_OFF      (OUT_SCALAR_OFF + 1)

// Workspace layout (bytes)
#define WS_WK1    0                                   // 512x1280 bf16 (full)
#define WS_WE2    (WS_WK1 + 512*1280*2)               // 1024x512
#define WS_WCB    (WS_WE2 + 1024*512*2)               // 256x1024
#define WS_WD1    (WS_WCB + 256*1024*2)               // 512x256
#define WS_WD2    (WS_WD1 + 512*256*2)                // 256x512
#define WS_WK2    (WS_WD2 + 256*512*2)                // 512x512
#define WS_WSTK   (WS_WK2 + 512*512*2)                // 1024x256 [We1 ; Wk1[:,:256]]
#define WS_BSTK   (WS_WSTK + 1024*256*2)              // 1024 fp32 [b_e1 | 0]
#define WS_KPART  (WS_BSTK + 1024*4)                  // Bn fp32 (zeroed by cvt)
#define WS_BUFA   (WS_KPART + (size_t)Bn*4)           // Bn x 1024 bf16: [h1|kp1] -> q
#define WS_BUFB   (WS_BUFA + (size_t)Bn*1024*2)       // Bn x 1024 bf16: logits -> mask
#define WS_BUFC   (WS_BUFB + (size_t)Bn*1024*2)       // Bn x 512 bf16: hk1 -> hd1
#define WS_WE2T   (WS_BUFC + (size_t)Bn*512*2)        // 512x1024 bf16 (We2 transposed)
#define WS_WCOMB2 (WS_WE2T + 512*1024*2)              // 512x512 bf16 (Wk1b @ We2)
#define WS_BCONST (WS_WCOMB2 + 512*512*2)             // 512 fp32

// cvt grid segmentation
#define CVT_BASE  2177       // weight f32->bf16 conversions + stacked W/bias
#define CVT_T     512        // We2 transpose
#define CVT_BC    128        // bconst GEMV (4 waves/block, 512 rows)
#define CVT_KZ    32         // kpart zeroing
#define CVT_GRID  (CVT_BASE + CVT_T + CVT_BC + CVT_KZ)   // 2849

__device__ inline void async_copy16(const void* g, void* l) {
    __builtin_amdgcn_global_load_lds(
        (const __attribute__((address_space(1))) void*)g,
        (__attribute__((address_space(3))) void*)l, 16, 0, 0);
}

__device__ inline void cv4(bf16* d, float4 v) {
    union { short4 s; bf16 h[4]; } u;
    u.h[0] = __float2bfloat16(v.x); u.h[1] = __float2bfloat16(v.y);
    u.h[2] = __float2bfloat16(v.z); u.h[3] = __float2bfloat16(v.w);
    *(short4*)d = u.s;
}

// ---------------------------------------------------------------------------
// One-shot prep: all weight bf16 conversions, stacked [We1;Wk1a] + bias,
// We2 transpose, bconst = Wk1b . b_e2 + b_k1, kpart zeroing.
// ---------------------------------------------------------------------------
__global__ __launch_bounds__(256) void cvt_kernel(
    const float* __restrict__ We1, const float* __restrict__ We2,
    const float* __restrict__ Wcb, const float* __restrict__ Wd1,
    const float* __restrict__ Wd2, const float* __restrict__ Wk1,
    const float* __restrict__ Wk2, const float* __restrict__ be1,
    const float* __restrict__ be2, const float* __restrict__ bk1,
    char* __restrict__ ws)
{
    const int bx = blockIdx.x, tid = threadIdx.x;
    if (bx < CVT_BASE) {
        int id = bx * 256 + tid;
        const float* src; bf16* dst; int off;
        if      (id < 163840) { src = Wk1; dst = (bf16*)(ws + WS_WK1); off = id; }
        else if (id < 294912) { src = We2; dst = (bf16*)(ws + WS_WE2); off = id - 163840; }
        else if (id < 360448) { src = Wcb; dst = (bf16*)(ws + WS_WCB); off = id - 294912; }
        else if (id < 393216) { src = Wd1; dst = (bf16*)(ws + WS_WD1); off = id - 360448; }
        else if (id < 425984) { src = Wd2; dst = (bf16*)(ws + WS_WD2); off = id - 393216; }
        else if (id < 491520) { src = Wk2; dst = (bf16*)(ws + WS_WK2); off = id - 425984; }
        else if (id < 524288) { src = We1; dst = (bf16*)(ws + WS_WSTK); off = id - 491520; }
        else if (id < 557056) {           // Wk1[:, :256] -> wstk rows 512..1023
            int l = id - 524288; int r = l >> 6, c4 = (l & 63) * 4;
            float4 v = *(const float4*)(Wk1 + (size_t)r * 1280 + c4);
            cv4((bf16*)(ws + WS_WSTK) + 131072 + r * 256 + c4, v);
            return;
        } else {                           // bias_stk: [b_e1 | zeros], fp32
            int l = id - 557056;
            float4 v = (l < 128) ? *(const float4*)(be1 + l * 4)
                                 : make_float4(0.f, 0.f, 0.f, 0.f);
            *(float4*)((float*)(ws + WS_BSTK) + l * 4) = v;
            return;
        }
        float4 v = *(const float4*)(src + (size_t)off * 4);
        cv4(dst + (size_t)off * 4, v);
    } else if (bx < CVT_BASE + CVT_T) {
        // We2T[n][k] = We2[k][n]; n=0..511, k in groups of 4
        int local = (bx - CVT_BASE) * 256 + tid;      // 0..131071
        int n = local & 511;
        int k = (local >> 9) * 4;
        float4 v;
        v.x = We2[(size_t)(k + 0) * 512 + n];
        v.y = We2[(size_t)(k + 1) * 512 + n];
        v.z = We2[(size_t)(k + 2) * 512 + n];
        v.w = We2[(size_t)(k + 3) * 512 + n];
        cv4((bf16*)(ws + WS_WE2T) + (size_t)n * 1024 + k, v);
    } else if (bx < CVT_BASE + CVT_T + CVT_BC) {
        // bconst[r] = sum_k Wk1[r][256+k] * be2[k] + bk1[r]
        int r = (bx - CVT_BASE - CVT_T) * 4 + (tid >> 6);
        int lane = tid & 63;
        const float* wr = Wk1 + (size_t)r * 1280 + 256;
        float s = 0.f;
#pragma unroll
        for (int t = 0; t < 16; t++) {
            int j = lane + t * 64;
            s = fmaf(wr[j], be2[j], s);
        }
#pragma unroll
        for (int off = 32; off > 0; off >>= 1) s += __shfl_down(s, off);
        if (lane == 0) ((float*)(ws + WS_BCONST))[r] = s + bk1[r];
    } else {
        // zero kpart
        int idx = ((bx - CVT_BASE - CVT_T - CVT_BC) * 256 + tid) * 4;
        *(float4*)((float*)(ws + WS_KPART) + idx) = make_float4(0.f, 0.f, 0.f, 0.f);
    }
}

// ---------------------------------------------------------------------------
// bf16 MFMA GEMM: 128x128 tile, BK=64, 4 waves (2x2), 16x16x32 MFMA.
// GRID IS TRANSPOSED: blockIdx.x = M-chunk, blockIdx.y = N-chunk. Blocks
// sharing an A-slab differ by gridDim.x (multiple of 8) in linear id ->
// same XCD -> A-slab served from that XCD's L2 after one HBM fetch.
// XOR-swizzled LDS staging; coalesced bf16 epilogue via LDS transpose.
// ASRC: 0 = A bf16 (global_load_lds); 1 = A fp32 (convert-stage).
// OMODE: 0 = bf16 C (coalesced); 1 = fp32 C; 2 = kdot epilogue (atomicAdd).
// relu_ncols (runtime): relu applied iff global col < relu_ncols.
// ACCIN: epilogue adds bf16 accin[row*ldacc + col] before relu.
// ---------------------------------------------------------------------------
template<int ASRC, int OMODE, int BIAS, int INVK, int ACCIN>
__global__ __launch_bounds__(256) void mgemm(
    const void* __restrict__ Ap, const u16* __restrict__ accin,
    const bf16* __restrict__ W, const float* __restrict__ bias,
    const float* __restrict__ kv, void* __restrict__ Cp,
    int N, int K, int lda, int ldw, int ldc, int ldacc, int relu_ncols)
{
    __shared__ __align__(16) char smem[32768];
    bf16* sA = (bf16*)smem;
    bf16* sB = (bf16*)(smem + 16384);

    const int tid = threadIdx.x;
    const int wv = tid >> 6, ln = tid & 63;
    const int wr = wv >> 1, wc = wv & 1;
    const int m0 = blockIdx.x * 128;   // M on x (fast dim) for XCD L2 locality
    const int n0 = blockIdx.y * 128;
    const int lm = ln & 15, q = ln >> 4;

    f32x4 acc[4][4];
#pragma unroll
    for (int i = 0; i < 4; i++)
#pragma unroll
        for (int j = 0; j < 4; j++)
            acc[i][j] = (f32x4){0.f, 0.f, 0.f, 0.f};

    for (int k0 = 0; k0 < K; k0 += 64) {
        if (ASRC == 0) {
            const bf16* A = (const bf16*)Ap;
#pragma unroll
            for (int i = 0; i < 4; i++) {
                int c = wv * 256 + i * 64 + ln;
                int row = c >> 3;
                int g = (c & 7) ^ (row & 7);
                async_copy16(A + (size_t)(m0 + row) * lda + k0 + g * 8, &sA[c * 8]);
            }
        } else {
            const float* Af = (const float*)Ap;
#pragma unroll
            for (int i = 0; i < 4; i++) {
                int c = wv * 256 + i * 64 + ln;
                int row = c >> 3;
                int g = (c & 7) ^ (row & 7);
                const float* src = Af + (size_t)(m0 + row) * lda + k0 + g * 8;
                float4 v0 = *(const float4*)src;
                float4 v1 = *(const float4*)(src + 4);
                union { frag8 s; bf16 h[8]; } u;
                u.h[0] = __float2bfloat16(v0.x); u.h[1] = __float2bfloat16(v0.y);
                u.h[2] = __float2bfloat16(v0.z); u.h[3] = __float2bfloat16(v0.w);
                u.h[4] = __float2bfloat16(v1.x); u.h[5] = __float2bfloat16(v1.y);
                u.h[6] = __float2bfloat16(v1.z); u.h[7] = __float2bfloat16(v1.w);
                *(frag8*)(&sA[c * 8]) = u.s;
            }
        }
#pragma unroll
        for (int i = 0; i < 4; i++) {
            int c = wv * 256 + i * 64 + ln;
            int row = c >> 3;
            int g = (c & 7) ^ (row & 7);
            async_copy16(W + (size_t)(n0 + row) * ldw + k0 + g * 8, &sB[c * 8]);
        }
        __syncthreads();

#pragma unroll
        for (int kk = 0; kk < 2; kk++) {
            frag8 af[4], bfr[4];
#pragma unroll
            for (int t = 0; t < 4; t++) {
                int r = wr * 64 + t * 16 + lm;
                af[t] = *(const frag8*)&sA[r * 64 + (((kk * 4 + q) ^ (r & 7)) * 8)];
                int n = wc * 64 + t * 16 + lm;
                bfr[t] = *(const frag8*)&sB[n * 64 + (((kk * 4 + q) ^ (n & 7)) * 8)];
            }
#pragma unroll
            for (int mt = 0; mt < 4; mt++)
#pragma unroll
                for (int nt = 0; nt < 4; nt++)
                    acc[mt][nt] = __builtin_amdgcn_mfma_f32_16x16x32_bf16(
                        af[mt], bfr[nt], acc[mt][nt], 0, 0, 0);
        }
        __syncthreads();
    }

    // ---- epilogue (C frag layout: col=lane&15, row=(lane>>4)*4+reg) ----
    if (OMODE == 2) {
        float* kpart = (float*)Cp;
#pragma unroll
        for (int mt = 0; mt < 4; mt++) {
#pragma unroll
            for (int r = 0; r < 4; r++) {
                int row = m0 + wr * 64 + mt * 16 + q * 4 + r;
                float s = 0.f;
#pragma unroll
                for (int nt = 0; nt < 4; nt++) {
                    int col = n0 + wc * 64 + nt * 16 + lm;
                    float v = acc[mt][nt][r] + bias[col];
                    v = fmaxf(v, 0.f);
                    s = fmaf(v, kv[col], s);
                }
#pragma unroll
                for (int off = 8; off > 0; off >>= 1) s += __shfl_down(s, off);
                if (lm == 0) atomicAdd(&kpart[row], s);
            }
        }
    } else if (OMODE == 1) {
#pragma unroll
        for (int mt = 0; mt < 4; mt++) {
#pragma unroll
            for (int r = 0; r < 4; r++) {
                int row = m0 + wr * 64 + mt * 16 + q * 4 + r;
#pragma unroll
                for (int nt = 0; nt < 4; nt++) {
                    int col = n0 + wc * 64 + nt * 16 + lm;
                    float v = acc[mt][nt][r];
                    if (BIAS) v += bias[col];
                    if (col < relu_ncols) v = fmaxf(v, 0.f);
                    ((float*)Cp)[(size_t)row * ldc + col] = v;
                }
            }
        }
    } else {
        u16* st = (u16*)smem;   // 128x128 bf16 = 32 KB (post-barrier overlay)
#pragma unroll
        for (int mt = 0; mt < 4; mt++) {
#pragma unroll
            for (int r = 0; r < 4; r++) {
                int rl = wr * 64 + mt * 16 + q * 4 + r;
                int rg = m0 + rl;
                float scale = 1.0f;
                if (INVK) scale = 1.0f / kv[rg];
#pragma unroll
                for (int nt = 0; nt < 4; nt++) {
                    int cl = wc * 64 + nt * 16 + lm;
                    int cg = n0 + cl;
                    float v = acc[mt][nt][r];
                    if (BIAS) v += bias[cg];
                    if (ACCIN) {
                        u16 raw = accin[(size_t)rg * ldacc + cg];
                        union { u16 u; bf16 h; } cu; cu.u = raw;
                        v += __bfloat162float(cu.h);
                    }
                    if (INVK) v *= scale;
                    if (cg < relu_ncols) v = fmaxf(v, 0.f);
                    union { u16 u; bf16 h; } ou; ou.h = __float2bfloat16(v);
                    st[rl * 128 + cl] = ou.u;
                }
            }
        }
        __syncthreads();
        u16* Cb = (u16*)Cp;
#pragma unroll
        for (int c = 0; c < 8; c++) {
            int idx = tid + c * 256;
            int rl = idx >> 4, cl = (idx & 15) * 8;
            *(uint4*)(Cb + (size_t)(m0 + rl) * ldc + n0 + cl) = ((const uint4*)st)[idx];
        }
    }
}

// ---------------------------------------------------------------------------
// khot + kfinal fused: wave-per-row. Computes k from kpart, writes kout/scl,
// then top-m mask on bf16 keys (2x8-bit radix, per-wave LDS histogram,
// no __syncthreads). Writes fp32 mask (d_out) + bf16 mask (in place).
// ---------------------------------------------------------------------------
__device__ inline void suffix_pick(const unsigned* h, int lane, unsigned target,
                                   unsigned& bucket, unsigned& rem)
{
    uint4 hv = *(const uint4*)(h + lane * 4);
    unsigned local = hv.x + hv.y + hv.z + hv.w;
    unsigned incl = local;
#pragma unroll
    for (int off = 1; off < 64; off <<= 1) {
        unsigned t = __shfl_down(incl, off);
        if (lane + off < 64) incl += t;
    }
    unsigned higher = incl - local;
    unsigned s3 = higher + hv.w;
    unsigned s2 = s3 + hv.z;
    unsigned s1 = s2 + hv.y;
    unsigned s0 = s1 + hv.x;
    unsigned suf[5] = {s0, s1, s2, s3, higher};
    int bj = -1; unsigned rm = 0;
#pragma unroll
    for (int j = 0; j < 4; j++)
        if (suf[j] >= target && suf[j + 1] < target) { bj = j; rm = target - suf[j + 1]; }
    unsigned long long mk = __ballot(bj >= 0);
    int src = (int)__ffsll((unsigned long long)mk) - 1;
    bucket = __shfl((unsigned)(lane * 4 + bj), src);
    rem    = __shfl(rm, src);
}

__global__ __launch_bounds__(256) void khot_kernel(
    u16* __restrict__ lb, const float* __restrict__ kpart,
    const float* __restrict__ b3, const float* __restrict__ kscale,
    float* __restrict__ mf, float* __restrict__ kout, float* __restrict__ scl)
{
    __shared__ unsigned hist[4][256];
    const int w = threadIdx.x >> 6, lane = threadIdx.x & 63;
    const int row = blockIdx.x * 4 + w;
    u16* rp = lb + (size_t)row * QDIM;
    float* mfp = mf + (size_t)row * QDIM;

    // k for this row (all lanes compute; lane 0 stores)
    float z = kpart[row] + b3[0];
    float kk = 1024.0f / (1.0f + expf(-z));
    float sc = 1.0f / (1.0f + expf(-kscale[0]));
    float kvv = fminf(fmaxf(kk * sc * 2.0f, 1.0f), 1024.0f);
    if (lane == 0) kout[row] = kvv;
    if (row == 0 && lane == 0) scl[0] = 0.0f;

    u16x8 v0 = *(const u16x8*)(rp + lane * 8);
    u16x8 v1 = *(const u16x8*)(rp + 512 + lane * 8);
    unsigned key[2][8];
#pragma unroll
    for (int j = 0; j < 8; j++) {
        unsigned a = v0[j], b = v1[j];
        key[0][j] = (a & 0x8000u) ? (~a & 0xffffu) : (a | 0x8000u);
        key[1][j] = (b & 0x8000u) ? (~b & 0xffffu) : (b | 0x8000u);
    }
    int mi = (int)ceilf(kvv);
    mi = mi < 1 ? 1 : (mi > QDIM ? QDIM : mi);
    const unsigned m = (unsigned)mi;
    unsigned* h = hist[w];

    *(uint4*)(h + lane * 4) = make_uint4(0, 0, 0, 0);
    __threadfence_block();
#pragma unroll
    for (int c = 0; c < 2; c++)
#pragma unroll
        for (int j = 0; j < 8; j++)
            atomicAdd(&h[key[c][j] >> 8], 1u);
    __threadfence_block();
    unsigned hi, rem1;
    suffix_pick(h, lane, m, hi, rem1);

    *(uint4*)(h + lane * 4) = make_uint4(0, 0, 0, 0);
    __threadfence_block();
#pragma unroll
    for (int c = 0; c < 2; c++)
#pragma unroll
        for (int j = 0; j < 8; j++)
            if ((key[c][j] >> 8) == hi) atomicAdd(&h[key[c][j] & 255u], 1u);
    __threadfence_block();
    unsigned lo, need;
    suffix_pick(h, lane, rem1, lo, need);

    const unsigned um = (hi << 8) | lo;

    unsigned cnt0 = 0, cnt1 = 0;
#pragma unroll
    for (int j = 0; j < 8; j++) { cnt0 += (key[0][j] == um); cnt1 += (key[1][j] == um); }
    unsigned pack = cnt0 | (cnt1 << 16);
    unsigned incl = pack;
#pragma unroll
    for (int off = 1; off < 64; off <<= 1) {
        unsigned t = __shfl_up(incl, off);
        if (lane >= off) incl += t;
    }
    unsigned excl = incl - pack;
    unsigned tot0 = __shfl(incl, 63) & 0xffffu;
    unsigned r0 = excl & 0xffffu;
    unsigned r1 = tot0 + (excl >> 16);

    float of[2][8];
    u16x8 mb0, mb1;
#pragma unroll
    for (int j = 0; j < 8; j++) {
        unsigned kv_ = key[0][j];
        bool s;
        if (kv_ > um) s = true;
        else if (kv_ == um) { s = (r0 < need); r0++; }
        else s = false;
        of[0][j] = s ? 1.0f : 0.0f;
        mb0[j] = s ? (u16)0x3F80 : (u16)0;
    }
#pragma unroll
    for (int j = 0; j < 8; j++) {
        unsigned kv_ = key[1][j];
        bool s;
        if (kv_ > um) s = true;
        else if (kv_ == um) { s = (r1 < need); r1++; }
        else s = false;
        of[1][j] = s ? 1.0f : 0.0f;
        mb1[j] = s ? (u16)0x3F80 : (u16)0;
    }
    *(float4*)(mfp + lane * 8)           = make_float4(of[0][0], of[0][1], of[0][2], of[0][3]);
    *(float4*)(mfp + lane * 8 + 4)       = make_float4(of[0][4], of[0][5], of[0][6], of[0][7]);
    *(float4*)(mfp + 512 + lane * 8)     = make_float4(of[1][0], of[1][1], of[1][2], of[1][3]);
    *(float4*)(mfp + 512 + lane * 8 + 4) = make_float4(of[1][4], of[1][5], of[1][6], of[1][7]);
    *(u16x8*)(rp + lane * 8)       = mb0;
    *(u16x8*)(rp + 512 + lane * 8) = mb1;
}

// ---------------------------------------------------------------------------
extern "C" void kernel_launch(void* const* d_in, const int* in_sizes, int n_in,
                              void* d_out, int out_size, void* d_ws, size_t ws_size,
                              hipStream_t stream) {
    const float* x     = (const float*)d_in[0];
    const float* W_e1  = (const float*)d_in[1];
    const float* b_e1  = (const float*)d_in[2];
    const float* W_e2  = (const float*)d_in[3];
    const float* b_e2  = (const float*)d_in[4];
    const float* W_cb  = (const float*)d_in[5];
    const float* W_d1  = (const float*)d_in[6];
    const float* b_d1  = (const float*)d_in[7];
    const float* W_d2  = (const float*)d_in[8];
    const float* b_d2  = (const float*)d_in[9];
    const float* W_k1  = (const float*)d_in[10];
    const float* b_k1  = (const float*)d_in[11];
    const float* W_k2  = (const float*)d_in[12];
    const float* b_k2  = (const float*)d_in[13];
    const float* W_k3  = (const float*)d_in[14];
    const float* b_k3  = (const float*)d_in[15];
    const float* k_scl = (const float*)d_in[16];

    float* out   = (float*)d_out;
    float* recon = out;
    float* maskf = out + OUT_KHOT_OFF;
    float* scl   = out + OUT_SCALAR_OFF;
    float* kout  = out + OUT_K_OFF;

    char* ws = (char*)d_ws;
    bf16* wb_k1  = (bf16*)(ws + WS_WK1);
    bf16* wb_e2  = (bf16*)(ws + WS_WE2);
    bf16* wb_cb  = (bf16*)(ws + WS_WCB);
    bf16* wb_d1  = (bf16*)(ws + WS_WD1);
    bf16* wb_d2  = (bf16*)(ws + WS_WD2);
    bf16* wb_k2  = (bf16*)(ws + WS_WK2);
    bf16* wstk   = (bf16*)(ws + WS_WSTK);
    float* bstk  = (float*)(ws + WS_BSTK);
    float* kpart = (float*)(ws + WS_KPART);
    bf16* bufA   = (bf16*)(ws + WS_BUFA);   // [h1 | kp1] 32768x1024; later q (ldc 256)
    bf16* bufB   = (bf16*)(ws + WS_BUFB);   // logits -> bf16 mask, 32768x1024
    bf16* bufC   = (bf16*)(ws + WS_BUFC);   // hk1 -> hd1, 32768x512
    bf16* we2t   = (bf16*)(ws + WS_WE2T);
    bf16* wcomb2 = (bf16*)(ws + WS_WCOMB2);
    float* bconst = (float*)(ws + WS_BCONST);

    const dim3 blk(256);
    const int FULL = 1 << 30;

    // prep: conversions + stacked W/b + We2T + bconst + kpart zero (1 launch)
    cvt_kernel<<<dim3(CVT_GRID), blk, 0, stream>>>(
        W_e1, W_e2, W_cb, W_d1, W_d2, W_k1, W_k2, b_e1, b_e2, b_k1, ws);

    // Wcomb2 = Wk1b @ We2  (M=512, N=512, K=1024) -> bf16
    mgemm<0, 0, 0, 0, 0><<<dim3(4, 4), blk, 0, stream>>>(
        wb_k1 + 256, nullptr, we2t, nullptr, nullptr, wcomb2,
        512, 1024, 1280, 1024, 512, 0, 0);

    // NOTE: all mgemm grids are (M-chunks, N-chunks) — M on x for XCD locality.
    // E1||K1a: [h1 | kp1] = x @ [We1;Wk1a]^T + [b_e1|0]; relu cols<512 only
    mgemm<1, 0, 1, 0, 0><<<dim3(Bn / 128, 8), blk, 0, stream>>>(
        x, nullptr, wstk, bstk, nullptr, bufA, 1024, 256, 256, 256, 1024, 0, 512);
    // K1b': hk1 = relu(h1 @ Wcomb2^T + kp1 + bconst) -> bufC   (K=512)
    mgemm<0, 0, 1, 0, 1><<<dim3(Bn / 128, 4), blk, 0, stream>>>(
        bufA, (const u16*)bufA + 512, wcomb2, bconst, nullptr, bufC,
        512, 512, 1024, 512, 512, 1024, FULL);
    // K2+kdot: kpart[row] += relu(hk1 @ Wk2^T + b_k2) . w3
    mgemm<0, 2, 1, 0, 0><<<dim3(Bn / 128, 4), blk, 0, stream>>>(
        bufC, nullptr, wb_k2, b_k2, W_k3, kpart, 512, 512, 512, 512, 512, 0, FULL);
    // E2: logits = h1 @ We2^T + b_e2 -> bufB (bf16; only khot consumes)
    mgemm<0, 0, 1, 0, 0><<<dim3(Bn / 128, 8), blk, 0, stream>>>(
        bufA, nullptr, wb_e2, b_e2, nullptr, bufB, 1024, 512, 1024, 512, 1024, 0, 0);
    // khot (+kfinal): logits -> fp32 mask (d_out) + bf16 mask; k -> kout/scl
    khot_kernel<<<dim3(Bn / 4), blk, 0, stream>>>(
        (u16*)bufB, kpart, b_k3, k_scl, maskf, kout, scl);
    // CB: q = (mask/k) @ Wcb^T -> bufA (ldc 256; [h1|kp1] dead)
    mgemm<0, 0, 0, 1, 0><<<dim3(Bn / 128, 2), blk, 0, stream>>>(
        bufB, nullptr, wb_cb, nullptr, kout, bufA, 256, 1024, 1024, 1024, 256, 0, 0);
    // D1: hd1 = relu(q @ Wd1^T + b_d1) -> bufC
    mgemm<0, 0, 1, 0, 0><<<dim3(Bn / 128, 4), blk, 0, stream>>>(
        bufA, nullptr, wb_d1, b_d1, nullptr, bufC, 512, 256, 256, 256, 512, 0, FULL);
    // D2: recon = hd1 @ Wd2^T + b_d2 -> d_out (fp32)
    mgemm<0, 1, 1, 0, 0><<<dim3(Bn / 128, 2), blk, 0, stream>>>(
        bufC, nullptr, wb_d2, b_d2, nullptr, recon, 256, 512, 512, 512, 256, 0, 0);
}

// Round 7
// 486.753 us; speedup vs baseline: 7.1853x; 1.0722x over previous
//
#include <hip/hip_runtime.h>
#include <hip/hip_bf16.h>
#include <math.h>

typedef __hip_bfloat16 bf16;
typedef unsigned short u16;
using frag8 = __attribute__((ext_vector_type(8))) short;   // 8 bf16 = 4 VGPRs
using f32x4 = __attribute__((ext_vector_type(4))) float;   // MFMA accumulator
using u16x8 = __attribute__((ext_vector_type(8))) unsigned short;

// Problem constants
#define Bn      32768
#define IN_DIM  256
#define N_HDIM  512
#define QDIM    1024
#define N_EMBD  256

// Output layout (float32): recon [B*256] | khot [B*1024] | scalar [1] | k [B]
#define OUT_KHOT_OFF   ((size_t)Bn * IN_DIM)
#define OUT_SCALAR_OFF (OUT_KHOT_OFF + (size_t)Bn * QDIM)
#define OUT_K_OFF      (OUT_SCALAR_OFF + 1)

// Workspace layout (bytes)
#define WS_WK1    0                                   // 512x1280 bf16 (full)
#define WS_WE2    (WS_WK1 + 512*1280*2)               // 1024x512
#define WS_WCB    (WS_WE2 + 1024*512*2)               // 256x1024
#define WS_WD1    (WS_WCB + 256*1024*2)               // 512x256
#define WS_WD2    (WS_WD1 + 512*256*2)                // 256x512
#define WS_WK2    (WS_WD2 + 256*512*2)                // 512x512
#define WS_WSTK   (WS_WK2 + 512*512*2)                // 1024x256 [We1 ; Wk1[:,:256]]
#define WS_BSTK   (WS_WSTK + 1024*256*2)              // 1024 fp32 [b_e1 | 0]
#define WS_KPART  (WS_BSTK + 1024*4)                  // Bn fp32 (zeroed by cvt)
#define WS_BUFA   (WS_KPART + (size_t)Bn*4)           // Bn x 1024 bf16: [h1|kp1] -> q
#define WS_BUFB   (WS_BUFA + (size_t)Bn*1024*2)       // Bn x 1024 bf16: logits -> mask
#define WS_BUFC   (WS_BUFB + (size_t)Bn*1024*2)       // Bn x 512 bf16: hk1 -> hd1
#define WS_WE2T   (WS_BUFC + (size_t)Bn*512*2)        // 512x1024 bf16 (We2 transposed)
#define WS_WCOMB2 (WS_WE2T + 512*1024*2)              // 512x512 bf16 (Wk1b @ We2)
#define WS_BCONST (WS_WCOMB2 + 512*512*2)             // 512 fp32

// cvt grid segmentation
#define CVT_BASE  2177
#define CVT_T     512
#define CVT_BC    128
#define CVT_KZ    32
#define CVT_GRID  (CVT_BASE + CVT_T + CVT_BC + CVT_KZ)   // 2849

__device__ inline void async_copy16(const void* g, void* l) {
    __builtin_amdgcn_global_load_lds(
        (const __attribute__((address_space(1))) void*)g,
        (__attribute__((address_space(3))) void*)l, 16, 0, 0);
}

__device__ inline void cv4(bf16* d, float4 v) {
    union { short4 s; bf16 h[4]; } u;
    u.h[0] = __float2bfloat16(v.x); u.h[1] = __float2bfloat16(v.y);
    u.h[2] = __float2bfloat16(v.z); u.h[3] = __float2bfloat16(v.w);
    *(short4*)d = u.s;
}

// ---------------------------------------------------------------------------
// One-shot prep: all weight bf16 conversions, stacked [We1;Wk1a] + bias,
// We2 transpose, bconst = Wk1b . b_e2 + b_k1, kpart zeroing.
// ---------------------------------------------------------------------------
__global__ __launch_bounds__(256) void cvt_kernel(
    const float* __restrict__ We1, const float* __restrict__ We2,
    const float* __restrict__ Wcb, const float* __restrict__ Wd1,
    const float* __restrict__ Wd2, const float* __restrict__ Wk1,
    const float* __restrict__ Wk2, const float* __restrict__ be1,
    const float* __restrict__ be2, const float* __restrict__ bk1,
    char* __restrict__ ws)
{
    const int bx = blockIdx.x, tid = threadIdx.x;
    if (bx < CVT_BASE) {
        int id = bx * 256 + tid;
        const float* src; bf16* dst; int off;
        if      (id < 163840) { src = Wk1; dst = (bf16*)(ws + WS_WK1); off = id; }
        else if (id < 294912) { src = We2; dst = (bf16*)(ws + WS_WE2); off = id - 163840; }
        else if (id < 360448) { src = Wcb; dst = (bf16*)(ws + WS_WCB); off = id - 294912; }
        else if (id < 393216) { src = Wd1; dst = (bf16*)(ws + WS_WD1); off = id - 360448; }
        else if (id < 425984) { src = Wd2; dst = (bf16*)(ws + WS_WD2); off = id - 393216; }
        else if (id < 491520) { src = Wk2; dst = (bf16*)(ws + WS_WK2); off = id - 425984; }
        else if (id < 524288) { src = We1; dst = (bf16*)(ws + WS_WSTK); off = id - 491520; }
        else if (id < 557056) {           // Wk1[:, :256] -> wstk rows 512..1023
            int l = id - 524288; int r = l >> 6, c4 = (l & 63) * 4;
            float4 v = *(const float4*)(Wk1 + (size_t)r * 1280 + c4);
            cv4((bf16*)(ws + WS_WSTK) + 131072 + r * 256 + c4, v);
            return;
        } else {                           // bias_stk: [b_e1 | zeros], fp32
            int l = id - 557056;
            float4 v = (l < 128) ? *(const float4*)(be1 + l * 4)
                                 : make_float4(0.f, 0.f, 0.f, 0.f);
            *(float4*)((float*)(ws + WS_BSTK) + l * 4) = v;
            return;
        }
        float4 v = *(const float4*)(src + (size_t)off * 4);
        cv4(dst + (size_t)off * 4, v);
    } else if (bx < CVT_BASE + CVT_T) {
        int local = (bx - CVT_BASE) * 256 + tid;
        int n = local & 511;
        int k = (local >> 9) * 4;
        float4 v;
        v.x = We2[(size_t)(k + 0) * 512 + n];
        v.y = We2[(size_t)(k + 1) * 512 + n];
        v.z = We2[(size_t)(k + 2) * 512 + n];
        v.w = We2[(size_t)(k + 3) * 512 + n];
        cv4((bf16*)(ws + WS_WE2T) + (size_t)n * 1024 + k, v);
    } else if (bx < CVT_BASE + CVT_T + CVT_BC) {
        int r = (bx - CVT_BASE - CVT_T) * 4 + (tid >> 6);
        int lane = tid & 63;
        const float* wr = Wk1 + (size_t)r * 1280 + 256;
        float s = 0.f;
#pragma unroll
        for (int t = 0; t < 16; t++) {
            int j = lane + t * 64;
            s = fmaf(wr[j], be2[j], s);
        }
#pragma unroll
        for (int off = 32; off > 0; off >>= 1) s += __shfl_down(s, off);
        if (lane == 0) ((float*)(ws + WS_BCONST))[r] = s + bk1[r];
    } else {
        int idx = ((bx - CVT_BASE - CVT_T - CVT_BC) * 256 + tid) * 4;
        *(float4*)((float*)(ws + WS_KPART) + idx) = make_float4(0.f, 0.f, 0.f, 0.f);
    }
}

// ---------------------------------------------------------------------------
// bf16 MFMA GEMM: 128(M) x 256(N) block tile, BK=64, 4 waves (2x2), each wave
// 64x128 (4x8 frags) -> FLOP/LDS-byte = 43.7 (MFMA-bound, vs 32 for 64x64).
// Grid: blockIdx.x = M-chunk (fast dim -> same-XCD A-slab reuse),
//       blockIdx.y = N-chunk.
// XOR-swizzled LDS staging; coalesced bf16 epilogue via 64 KB LDS store-stage.
// ASRC: 0 = A bf16 (global_load_lds); 1 = A fp32 (convert-stage).
// OMODE: 0 = bf16 C (coalesced); 1 = fp32 C; 2 = kdot epilogue (atomicAdd).
// relu_ncols (runtime): relu applied iff global col < relu_ncols.
// ACCIN: epilogue adds bf16 accin[row*ldacc + col] before relu.
// ---------------------------------------------------------------------------
template<int ASRC, int OMODE, int BIAS, int INVK, int ACCIN>
__global__ __launch_bounds__(256, 2) void mgemm(
    const void* __restrict__ Ap, const u16* __restrict__ accin,
    const bf16* __restrict__ W, const float* __restrict__ bias,
    const float* __restrict__ kv, void* __restrict__ Cp,
    int N, int K, int lda, int ldw, int ldc, int ldacc, int relu_ncols)
{
    __shared__ __align__(16) char smem[65536];
    bf16* sA = (bf16*)smem;               // 128 x 64 = 16 KB
    bf16* sB = (bf16*)(smem + 16384);     // 256 x 64 = 32 KB

    const int tid = threadIdx.x;
    const int wv = tid >> 6, ln = tid & 63;
    const int wr = wv >> 1, wc = wv & 1;
    const int m0 = blockIdx.x * 128;   // M on x (fast dim) for XCD L2 locality
    const int n0 = blockIdx.y * 256;
    const int lm = ln & 15, q = ln >> 4;

    f32x4 acc[4][8];
#pragma unroll
    for (int i = 0; i < 4; i++)
#pragma unroll
        for (int j = 0; j < 8; j++)
            acc[i][j] = (f32x4){0.f, 0.f, 0.f, 0.f};

    for (int k0 = 0; k0 < K; k0 += 64) {
        // ---- stage A (128 rows x 64 k) ----
        if (ASRC == 0) {
            const bf16* A = (const bf16*)Ap;
#pragma unroll
            for (int i = 0; i < 4; i++) {
                int c = wv * 256 + i * 64 + ln;
                int row = c >> 3;
                int g = (c & 7) ^ (row & 7);
                async_copy16(A + (size_t)(m0 + row) * lda + k0 + g * 8, &sA[c * 8]);
            }
        } else {
            const float* Af = (const float*)Ap;
#pragma unroll
            for (int i = 0; i < 4; i++) {
                int c = wv * 256 + i * 64 + ln;
                int row = c >> 3;
                int g = (c & 7) ^ (row & 7);
                const float* src = Af + (size_t)(m0 + row) * lda + k0 + g * 8;
                float4 v0 = *(const float4*)src;
                float4 v1 = *(const float4*)(src + 4);
                union { frag8 s; bf16 h[8]; } u;
                u.h[0] = __float2bfloat16(v0.x); u.h[1] = __float2bfloat16(v0.y);
                u.h[2] = __float2bfloat16(v0.z); u.h[3] = __float2bfloat16(v0.w);
                u.h[4] = __float2bfloat16(v1.x); u.h[5] = __float2bfloat16(v1.y);
                u.h[6] = __float2bfloat16(v1.z); u.h[7] = __float2bfloat16(v1.w);
                *(frag8*)(&sA[c * 8]) = u.s;
            }
        }
        // ---- stage W tile (256 rows x 64 k) ----
#pragma unroll
        for (int i = 0; i < 8; i++) {
            int c = wv * 512 + i * 64 + ln;
            int row = c >> 3;
            int g = (c & 7) ^ (row & 7);
            async_copy16(W + (size_t)(n0 + row) * ldw + k0 + g * 8, &sB[c * 8]);
        }
        __syncthreads();

#pragma unroll
        for (int kk = 0; kk < 2; kk++) {
            frag8 af[4], bfr[8];
#pragma unroll
            for (int t = 0; t < 4; t++) {
                int r = wr * 64 + t * 16 + lm;
                af[t] = *(const frag8*)&sA[r * 64 + (((kk * 4 + q) ^ (r & 7)) * 8)];
            }
#pragma unroll
            for (int t = 0; t < 8; t++) {
                int n = wc * 128 + t * 16 + lm;
                bfr[t] = *(const frag8*)&sB[n * 64 + (((kk * 4 + q) ^ (n & 7)) * 8)];
            }
#pragma unroll
            for (int mt = 0; mt < 4; mt++)
#pragma unroll
                for (int nt = 0; nt < 8; nt++)
                    acc[mt][nt] = __builtin_amdgcn_mfma_f32_16x16x32_bf16(
                        af[mt], bfr[nt], acc[mt][nt], 0, 0, 0);
        }
        __syncthreads();
    }

    // ---- epilogue (C frag layout: col=lane&15, row=(lane>>4)*4+reg) ----
    if (OMODE == 2) {
        float* kpart = (float*)Cp;
#pragma unroll
        for (int mt = 0; mt < 4; mt++) {
#pragma unroll
            for (int r = 0; r < 4; r++) {
                int row = m0 + wr * 64 + mt * 16 + q * 4 + r;
                float s = 0.f;
#pragma unroll
                for (int nt = 0; nt < 8; nt++) {
                    int col = n0 + wc * 128 + nt * 16 + lm;
                    float v = acc[mt][nt][r] + bias[col];
                    v = fmaxf(v, 0.f);
                    s = fmaf(v, kv[col], s);
                }
#pragma unroll
                for (int off = 8; off > 0; off >>= 1) s += __shfl_down(s, off);
                if (lm == 0) atomicAdd(&kpart[row], s);
            }
        }
    } else if (OMODE == 1) {
#pragma unroll
        for (int mt = 0; mt < 4; mt++) {
#pragma unroll
            for (int r = 0; r < 4; r++) {
                int row = m0 + wr * 64 + mt * 16 + q * 4 + r;
#pragma unroll
                for (int nt = 0; nt < 8; nt++) {
                    int col = n0 + wc * 128 + nt * 16 + lm;
                    float v = acc[mt][nt][r];
                    if (BIAS) v += bias[col];
                    if (col < relu_ncols) v = fmaxf(v, 0.f);
                    ((float*)Cp)[(size_t)row * ldc + col] = v;
                }
            }
        }
    } else {
        u16* st = (u16*)smem;   // 128 x 256 bf16 = 64 KB (post-barrier overlay)
#pragma unroll
        for (int mt = 0; mt < 4; mt++) {
#pragma unroll
            for (int r = 0; r < 4; r++) {
                int rl = wr * 64 + mt * 16 + q * 4 + r;
                int rg = m0 + rl;
                float scale = 1.0f;
                if (INVK) scale = 1.0f / kv[rg];
#pragma unroll
                for (int nt = 0; nt < 8; nt++) {
                    int cl = wc * 128 + nt * 16 + lm;
                    int cg = n0 + cl;
                    float v = acc[mt][nt][r];
                    if (BIAS) v += bias[cg];
                    if (ACCIN) {
                        u16 raw = accin[(size_t)rg * ldacc + cg];
                        union { u16 u; bf16 h; } cu; cu.u = raw;
                        v += __bfloat162float(cu.h);
                    }
                    if (INVK) v *= scale;
                    if (cg < relu_ncols) v = fmaxf(v, 0.f);
                    union { u16 u; bf16 h; } ou; ou.h = __float2bfloat16(v);
                    st[rl * 256 + cl] = ou.u;
                }
            }
        }
        __syncthreads();
        u16* Cb = (u16*)Cp;
#pragma unroll
        for (int c = 0; c < 16; c++) {
            int idx = tid + c * 256;              // 0..4095 chunks of 8 bf16
            int rl = idx >> 5, cl = (idx & 31) * 8;
            *(uint4*)(Cb + (size_t)(m0 + rl) * ldc + n0 + cl) = ((const uint4*)st)[idx];
        }
    }
}

// ---------------------------------------------------------------------------
// khot + kfinal fused: wave-per-row. Computes k from kpart, writes kout/scl,
// then top-m mask on bf16 keys (2x8-bit radix, per-wave LDS histogram,
// no __syncthreads). Writes fp32 mask (d_out) + bf16 mask (in place).
// ---------------------------------------------------------------------------
__device__ inline void suffix_pick(const unsigned* h, int lane, unsigned target,
                                   unsigned& bucket, unsigned& rem)
{
    uint4 hv = *(const uint4*)(h + lane * 4);
    unsigned local = hv.x + hv.y + hv.z + hv.w;
    unsigned incl = local;
#pragma unroll
    for (int off = 1; off < 64; off <<= 1) {
        unsigned t = __shfl_down(incl, off);
        if (lane + off < 64) incl += t;
    }
    unsigned higher = incl - local;
    unsigned s3 = higher + hv.w;
    unsigned s2 = s3 + hv.z;
    unsigned s1 = s2 + hv.y;
    unsigned s0 = s1 + hv.x;
    unsigned suf[5] = {s0, s1, s2, s3, higher};
    int bj = -1; unsigned rm = 0;
#pragma unroll
    for (int j = 0; j < 4; j++)
        if (suf[j] >= target && suf[j + 1] < target) { bj = j; rm = target - suf[j + 1]; }
    unsigned long long mk = __ballot(bj >= 0);
    int src = (int)__ffsll((unsigned long long)mk) - 1;
    bucket = __shfl((unsigned)(lane * 4 + bj), src);
    rem    = __shfl(rm, src);
}

__global__ __launch_bounds__(256) void khot_kernel(
    u16* __restrict__ lb, const float* __restrict__ kpart,
    const float* __restrict__ b3, const float* __restrict__ kscale,
    float* __restrict__ mf, float* __restrict__ kout, float* __restrict__ scl)
{
    __shared__ unsigned hist[4][256];
    const int w = threadIdx.x >> 6, lane = threadIdx.x & 63;
    const int row = blockIdx.x * 4 + w;
    u16* rp = lb + (size_t)row * QDIM;
    float* mfp = mf + (size_t)row * QDIM;

    float z = kpart[row] + b3[0];
    float kk = 1024.0f / (1.0f + expf(-z));
    float sc = 1.0f / (1.0f + expf(-kscale[0]));
    float kvv = fminf(fmaxf(kk * sc * 2.0f, 1.0f), 1024.0f);
    if (lane == 0) kout[row] = kvv;
    if (row == 0 && lane == 0) scl[0] = 0.0f;

    u16x8 v0 = *(const u16x8*)(rp + lane * 8);
    u16x8 v1 = *(const u16x8*)(rp + 512 + lane * 8);
    unsigned key[2][8];
#pragma unroll
    for (int j = 0; j < 8; j++) {
        unsigned a = v0[j], b = v1[j];
        key[0][j] = (a & 0x8000u) ? (~a & 0xffffu) : (a | 0x8000u);
        key[1][j] = (b & 0x8000u) ? (~b & 0xffffu) : (b | 0x8000u);
    }
    int mi = (int)ceilf(kvv);
    mi = mi < 1 ? 1 : (mi > QDIM ? QDIM : mi);
    const unsigned m = (unsigned)mi;
    unsigned* h = hist[w];

    *(uint4*)(h + lane * 4) = make_uint4(0, 0, 0, 0);
    __threadfence_block();
#pragma unroll
    for (int c = 0; c < 2; c++)
#pragma unroll
        for (int j = 0; j < 8; j++)
            atomicAdd(&h[key[c][j] >> 8], 1u);
    __threadfence_block();
    unsigned hi, rem1;
    suffix_pick(h, lane, m, hi, rem1);

    *(uint4*)(h + lane * 4) = make_uint4(0, 0, 0, 0);
    __threadfence_block();
#pragma unroll
    for (int c = 0; c < 2; c++)
#pragma unroll
        for (int j = 0; j < 8; j++)
            if ((key[c][j] >> 8) == hi) atomicAdd(&h[key[c][j] & 255u], 1u);
    __threadfence_block();
    unsigned lo, need;
    suffix_pick(h, lane, rem1, lo, need);

    const unsigned um = (hi << 8) | lo;

    unsigned cnt0 = 0, cnt1 = 0;
#pragma unroll
    for (int j = 0; j < 8; j++) { cnt0 += (key[0][j] == um); cnt1 += (key[1][j] == um); }
    unsigned pack = cnt0 | (cnt1 << 16);
    unsigned incl = pack;
#pragma unroll
    for (int off = 1; off < 64; off <<= 1) {
        unsigned t = __shfl_up(incl, off);
        if (lane >= off) incl += t;
    }
    unsigned excl = incl - pack;
    unsigned tot0 = __shfl(incl, 63) & 0xffffu;
    unsigned r0 = excl & 0xffffu;
    unsigned r1 = tot0 + (excl >> 16);

    float of[2][8];
    u16x8 mb0, mb1;
#pragma unroll
    for (int j = 0; j < 8; j++) {
        unsigned kv_ = key[0][j];
        bool s;
        if (kv_ > um) s = true;
        else if (kv_ == um) { s = (r0 < need); r0++; }
        else s = false;
        of[0][j] = s ? 1.0f : 0.0f;
        mb0[j] = s ? (u16)0x3F80 : (u16)0;
    }
#pragma unroll
    for (int j = 0; j < 8; j++) {
        unsigned kv_ = key[1][j];
        bool s;
        if (kv_ > um) s = true;
        else if (kv_ == um) { s = (r1 < need); r1++; }
        else s = false;
        of[1][j] = s ? 1.0f : 0.0f;
        mb1[j] = s ? (u16)0x3F80 : (u16)0;
    }
    *(float4*)(mfp + lane * 8)           = make_float4(of[0][0], of[0][1], of[0][2], of[0][3]);
    *(float4*)(mfp + lane * 8 + 4)       = make_float4(of[0][4], of[0][5], of[0][6], of[0][7]);
    *(float4*)(mfp + 512 + lane * 8)     = make_float4(of[1][0], of[1][1], of[1][2], of[1][3]);
    *(float4*)(mfp + 512 + lane * 8 + 4) = make_float4(of[1][4], of[1][5], of[1][6], of[1][7]);
    *(u16x8*)(rp + lane * 8)       = mb0;
    *(u16x8*)(rp + 512 + lane * 8) = mb1;
}

// ---------------------------------------------------------------------------
extern "C" void kernel_launch(void* const* d_in, const int* in_sizes, int n_in,
                              void* d_out, int out_size, void* d_ws, size_t ws_size,
                              hipStream_t stream) {
    const float* x     = (const float*)d_in[0];
    const float* W_e1  = (const float*)d_in[1];
    const float* b_e1  = (const float*)d_in[2];
    const float* W_e2  = (const float*)d_in[3];
    const float* b_e2  = (const float*)d_in[4];
    const float* W_cb  = (const float*)d_in[5];
    const float* W_d1  = (const float*)d_in[6];
    const float* b_d1  = (const float*)d_in[7];
    const float* W_d2  = (const float*)d_in[8];
    const float* b_d2  = (const float*)d_in[9];
    const float* W_k1  = (const float*)d_in[10];
    const float* b_k1  = (const float*)d_in[11];
    const float* W_k2  = (const float*)d_in[12];
    const float* b_k2  = (const float*)d_in[13];
    const float* W_k3  = (const float*)d_in[14];
    const float* b_k3  = (const float*)d_in[15];
    const float* k_scl = (const float*)d_in[16];

    float* out   = (float*)d_out;
    float* recon = out;
    float* maskf = out + OUT_KHOT_OFF;
    float* scl   = out + OUT_SCALAR_OFF;
    float* kout  = out + OUT_K_OFF;

    char* ws = (char*)d_ws;
    bf16* wb_k1  = (bf16*)(ws + WS_WK1);
    bf16* wb_e2  = (bf16*)(ws + WS_WE2);
    bf16* wb_cb  = (bf16*)(ws + WS_WCB);
    bf16* wb_d1  = (bf16*)(ws + WS_WD1);
    bf16* wb_d2  = (bf16*)(ws + WS_WD2);
    bf16* wb_k2  = (bf16*)(ws + WS_WK2);
    bf16* wstk   = (bf16*)(ws + WS_WSTK);
    float* bstk  = (float*)(ws + WS_BSTK);
    float* kpart = (float*)(ws + WS_KPART);
    bf16* bufA   = (bf16*)(ws + WS_BUFA);   // [h1 | kp1] 32768x1024; later q (ldc 256)
    bf16* bufB   = (bf16*)(ws + WS_BUFB);   // logits -> bf16 mask, 32768x1024
    bf16* bufC   = (bf16*)(ws + WS_BUFC);   // hk1 -> hd1, 32768x512
    bf16* we2t   = (bf16*)(ws + WS_WE2T);
    bf16* wcomb2 = (bf16*)(ws + WS_WCOMB2);
    float* bconst = (float*)(ws + WS_BCONST);

    const dim3 blk(256);
    const int FULL = 1 << 30;

    // prep: conversions + stacked W/b + We2T + bconst + kpart zero (1 launch)
    cvt_kernel<<<dim3(CVT_GRID), blk, 0, stream>>>(
        W_e1, W_e2, W_cb, W_d1, W_d2, W_k1, W_k2, b_e1, b_e2, b_k1, ws);

    // Wcomb2 = Wk1b @ We2  (M=512, N=512, K=1024) -> bf16
    mgemm<0, 0, 0, 0, 0><<<dim3(4, 2), blk, 0, stream>>>(
        wb_k1 + 256, nullptr, we2t, nullptr, nullptr, wcomb2,
        512, 1024, 1280, 1024, 512, 0, 0);

    // grids are (M-chunks of 128, N-chunks of 256) — M on x for XCD locality.
    // E1||K1a: [h1 | kp1] = x @ [We1;Wk1a]^T + [b_e1|0]; relu cols<512 only
    mgemm<1, 0, 1, 0, 0><<<dim3(Bn / 128, 4), blk, 0, stream>>>(
        x, nullptr, wstk, bstk, nullptr, bufA, 1024, 256, 256, 256, 1024, 0, 512);
    // K1b': hk1 = relu(h1 @ Wcomb2^T + kp1 + bconst) -> bufC   (K=512)
    mgemm<0, 0, 1, 0, 1><<<dim3(Bn / 128, 2), blk, 0, stream>>>(
        bufA, (const u16*)bufA + 512, wcomb2, bconst, nullptr, bufC,
        512, 512, 1024, 512, 512, 1024, FULL);
    // K2+kdot: kpart[row] += relu(hk1 @ Wk2^T + b_k2) . w3
    mgemm<0, 2, 1, 0, 0><<<dim3(Bn / 128, 2), blk, 0, stream>>>(
        bufC, nullptr, wb_k2, b_k2, W_k3, kpart, 512, 512, 512, 512, 512, 0, FULL);
    // E2: logits = h1 @ We2^T + b_e2 -> bufB (bf16; only khot consumes)
    mgemm<0, 0, 1, 0, 0><<<dim3(Bn / 128, 4), blk, 0, stream>>>(
        bufA, nullptr, wb_e2, b_e2, nullptr, bufB, 1024, 512, 1024, 512, 1024, 0, 0);
    // khot (+kfinal): logits -> fp32 mask (d_out) + bf16 mask; k -> kout/scl
    khot_kernel<<<dim3(Bn / 4), blk, 0, stream>>>(
        (u16*)bufB, kpart, b_k3, k_scl, maskf, kout, scl);
    // CB: q = (mask/k) @ Wcb^T -> bufA (ldc 256; [h1|kp1] dead)
    mgemm<0, 0, 0, 1, 0><<<dim3(Bn / 128, 1), blk, 0, stream>>>(
        bufB, nullptr, wb_cb, nullptr, kout, bufA, 256, 1024, 1024, 1024, 256, 0, 0);
    // D1: hd1 = relu(q @ Wd1^T + b_d1) -> bufC
    mgemm<0, 0, 1, 0, 0><<<dim3(Bn / 128, 2), blk, 0, stream>>>(
        bufA, nullptr, wb_d1, b_d1, nullptr, bufC, 512, 256, 256, 256, 512, 0, FULL);
    // D2: recon = hd1 @ Wd2^T + b_d2 -> d_out (fp32)
    mgemm<0, 1, 1, 0, 0><<<dim3(Bn / 128, 1), blk, 0, stream>>>(
        bufC, nullptr, wb_d2, b_d2, nullptr, recon, 256, 512, 512, 512, 256, 0, 0);
}